// Round 13
// baseline (408.477 us; speedup 1.0000x reference)
//
#include <hip/hip_runtime.h>
#include <math.h>

#define NN 4096
#define DD 128
#define ALPHA_C 16.0f
#define KSEL 32         // threshold = (K+1)-th smallest, 0-based index K
#define P1F -0.245f     // pivots bracketing rank-32 for N(0,1/128) sims
#define P2F -0.19f

typedef __attribute__((ext_vector_type(8))) short bf16x8;
typedef __attribute__((ext_vector_type(4))) float f32x4;

// ---- float <-> order-preserving u32 key ----
__device__ __forceinline__ unsigned f2k(float f) {
  unsigned b = __float_as_uint(f);
  return (b & 0x80000000u) ? ~b : (b | 0x80000000u);
}
__device__ __forceinline__ float k2f(unsigned k) {
  unsigned b = (k & 0x80000000u) ? (k & 0x7FFFFFFFu) : ~k;
  return __uint_as_float(b);
}

// ---- wave (64-lane) butterfly reductions ----
__device__ __forceinline__ double wsum_d(double v) {
  #pragma unroll
  for (int m = 32; m; m >>= 1) v += __shfl_xor(v, m, 64);
  return v;
}
__device__ __forceinline__ int wsum_i(int v) {
  #pragma unroll
  for (int m = 32; m; m >>= 1) v += __shfl_xor(v, m, 64);
  return v;
}
__device__ __forceinline__ float wsum_f(float v) {
  #pragma unroll
  for (int m = 32; m; m >>= 1) v += __shfl_xor(v, m, 64);
  return v;
}
__device__ __forceinline__ float wmin_f(float v) {
  #pragma unroll
  for (int m = 32; m; m >>= 1) v = fminf(v, __shfl_xor(v, m, 64));
  return v;
}

// ---- kernel 1: split x -> bf16 hi/lo fragment-major; zero counters ----
__global__ __launch_bounds__(256) void nca_prep(
    const float* __restrict__ x, short* __restrict__ xhi, short* __restrict__ xlo,
    int* __restrict__ wincnt, int* __restrict__ flag) {
  const int f  = blockIdx.x * blockDim.x + threadIdx.x;  // 0 .. N*D/8-1
  if (f < NN) wincnt[f] = 0;
  if (f == NN) flag[0] = 0;
  const int l  = f & 63;
  const int kb = (f >> 6) & 3;
  const int rg = f >> 8;
  const int row = (rg << 4) + (l & 15);
  const int k0  = (kb << 5) + ((l >> 4) << 3);
  const float* src = x + (size_t)row * DD + k0;
  float4 v0 = *reinterpret_cast<const float4*>(src);
  float4 v1 = *reinterpret_cast<const float4*>(src + 4);
  float vv[8] = {v0.x, v0.y, v0.z, v0.w, v1.x, v1.y, v1.z, v1.w};
  bf16x8 h, lo;
  #pragma unroll
  for (int q = 0; q < 8; ++q) {
    unsigned u  = __float_as_uint(vv[q]);
    unsigned hb = (u + 0x7FFFu + ((u >> 16) & 1u)) >> 16;
    float hf    = __uint_as_float(hb << 16);
    float lf    = vv[q] - hf;
    unsigned ul = __float_as_uint(lf);
    unsigned lb = (ul + 0x7FFFu + ((ul >> 16) & 1u)) >> 16;
    h[q] = (short)hb; lo[q] = (short)lb;
  }
  *reinterpret_cast<bf16x8*>(xhi + (size_t)f * 8) = h;
  *reinterpret_cast<bf16x8*>(xlo + (size_t)f * 8) = lo;
}

// ---- kernel 2: fused MFMA GEMM + selection epilogue (split-K partials) ----
// Per (row, colblock cg): partial record of 8 u32 slots:
// 0 base_sum f32 | 1 pes f32 (sum exp(-a*s), pos, s<P1) | 2 nes f32 (neg)
// 3 minp f32 (min valid_pos sim) | 4 c1|pc1<<16 | 5 pos_s f32 (diag)
// 6 neg_s f32 (diag) | 7 pos_c|neg_c<<16 (diag). Self (j==i) skipped
// everywhere except base; handled in combine via f64 self-dot.
// Window values (key in [P1,P2)) appended to winbuf[row][<64] via atomics.
__global__ __launch_bounds__(256) void nca_gemm(
    const short* __restrict__ xhi, const short* __restrict__ xlo,
    const int* __restrict__ tgt, unsigned* __restrict__ part,
    uint2* __restrict__ winbuf, int* __restrict__ wincnt) {
  __shared__ unsigned state[4][32][8];   // 4 KB: per-wave per-row partials

  const int tid = threadIdx.x;
  const int w   = tid >> 6;
  const int l   = tid & 63;
  const int rg  = blockIdx.x >> 4;
  const int cg  = blockIdx.x & 15;
  const int R   = rg << 5;                 // 32 rows
  const int C   = (cg << 8) + (w << 6);    // 64 cols per wave
  const int rga = rg << 1;
  const int rgb = (cg << 4) + (w << 2);

  f32x4 acc[2][4];
  #pragma unroll
  for (int rt = 0; rt < 2; ++rt)
    #pragma unroll
    for (int t = 0; t < 4; ++t) acc[rt][t] = (f32x4){0.f, 0.f, 0.f, 0.f};

  #pragma unroll
  for (int kb = 0; kb < 4; ++kb) {
    bf16x8 ah[2], al[2], bh[4], bl[4];
    #pragma unroll
    for (int rt = 0; rt < 2; ++rt) {
      const size_t off = ((size_t)((rga + rt) * 4 + kb) * 64 + l) * 8;
      ah[rt] = *reinterpret_cast<const bf16x8*>(xhi + off);
      al[rt] = *reinterpret_cast<const bf16x8*>(xlo + off);
    }
    #pragma unroll
    for (int t = 0; t < 4; ++t) {
      const size_t off = ((size_t)((rgb + t) * 4 + kb) * 64 + l) * 8;
      bh[t] = *reinterpret_cast<const bf16x8*>(xhi + off);
      bl[t] = *reinterpret_cast<const bf16x8*>(xlo + off);
    }
    #pragma unroll
    for (int rt = 0; rt < 2; ++rt)
      #pragma unroll
      for (int t = 0; t < 4; ++t) {
        acc[rt][t] = __builtin_amdgcn_mfma_f32_16x16x32_bf16(ah[rt], bh[t], acc[rt][t], 0, 0, 0);
        acc[rt][t] = __builtin_amdgcn_mfma_f32_16x16x32_bf16(ah[rt], bl[t], acc[rt][t], 0, 0, 0);
        acc[rt][t] = __builtin_amdgcn_mfma_f32_16x16x32_bf16(al[rt], bh[t], acc[rt][t], 0, 0, 0);
      }
  }

  // ---- selection epilogue ----
  // C/D layout (m89-verified): col = lane&15, row = (lane>>4)*4 + reg
  const int rbase = (l >> 4) << 2;
  const int cc    = l & 15;
  const unsigned P1k = f2k(P1F), P2k = f2k(P2F);
  const bool diagblk = (R + 32 == NN);     // block containing row NN-1

  int tr[2][4], tc[4];
  #pragma unroll
  for (int rt = 0; rt < 2; ++rt)
    #pragma unroll
    for (int r = 0; r < 4; ++r) tr[rt][r] = tgt[R + (rt << 4) + rbase + r];
  #pragma unroll
  for (int t = 0; t < 4; ++t) tc[t] = tgt[C + (t << 4) + cc];

  #pragma unroll
  for (int rt = 0; rt < 2; ++rt) {
    #pragma unroll
    for (int r = 0; r < 4; ++r) {
      const int row_l = (rt << 4) + rbase + r;
      const int grow  = R + row_l;
      float base4 = 0.f, pes4 = 0.f, nes4 = 0.f, minp4 = __builtin_inff();
      float pos4 = 0.f, neg4 = 0.f;
      int cnts4 = 0;   // bytes: c1 | pc1<<8 | pos_c<<16 | neg_c<<24 (each <=4)
      #pragma unroll
      for (int t = 0; t < 4; ++t) {
        const float s = acc[rt][t][r];
        const int j = C + (t << 4) + cc;
        base4 += s;                          // base includes self
        if (j != grow) {
          const bool same = (tc[t] == tr[rt][r]);
          const unsigned key = f2k(s);
          if (key < P1k) {                   // below lower pivot: accumulate
            const float e = expf(-ALPHA_C * s);
            cnts4 += 1;
            if (same) { pes4 += e; cnts4 += (1 << 8); }
            else nes4 += e;
          } else if (key < P2k) {            // window candidate
            int p = atomicAdd(&wincnt[grow], 1);
            if (p < 64) winbuf[(size_t)grow * 64 + p] = make_uint2(key, same ? 1u : 0u);
          }
          if (same) {
            if (s < 1.0f) {
              minp4 = fminf(minp4, s);
              if (diagblk) { pos4 += s; cnts4 += (1 << 16); }
            }
          } else if (diagblk) { neg4 += s; cnts4 += (1 << 24); }
        }
      }
      // combine the 16 lanes sharing this row (xor masks stay in-quarter)
      #pragma unroll
      for (int m = 1; m < 16; m <<= 1) {
        base4 += __shfl_xor(base4, m, 64);
        pes4  += __shfl_xor(pes4,  m, 64);
        nes4  += __shfl_xor(nes4,  m, 64);
        minp4  = fminf(minp4, __shfl_xor(minp4, m, 64));
        cnts4 += __shfl_xor(cnts4, m, 64);
        if (diagblk) {
          pos4 += __shfl_xor(pos4, m, 64);
          neg4 += __shfl_xor(neg4, m, 64);
        }
      }
      if ((l & 15) == 0) {
        unsigned* st = &state[w][row_l][0];
        st[0] = __float_as_uint(base4); st[1] = __float_as_uint(pes4);
        st[2] = __float_as_uint(nes4);  st[3] = __float_as_uint(minp4);
        st[4] = (unsigned)cnts4;        st[5] = __float_as_uint(pos4);
        st[6] = __float_as_uint(neg4);  st[7] = (unsigned)cnts4;
      }
    }
  }
  __syncthreads();

  // cross-wave combine: thread -> (row, field); widen packed counts to u16
  {
    const int row = tid >> 3, fld = tid & 7;
    unsigned v0 = state[0][row][fld], v1 = state[1][row][fld];
    unsigned v2 = state[2][row][fld], v3 = state[3][row][fld];
    unsigned res;
    if (fld == 4) {
      unsigned a = (v0 & 255) + (v1 & 255) + (v2 & 255) + (v3 & 255);
      unsigned b = ((v0 >> 8) & 255) + ((v1 >> 8) & 255) + ((v2 >> 8) & 255) + ((v3 >> 8) & 255);
      res = a | (b << 16);
    } else if (fld == 7) {
      unsigned a = ((v0 >> 16) & 255) + ((v1 >> 16) & 255) + ((v2 >> 16) & 255) + ((v3 >> 16) & 255);
      unsigned b = (v0 >> 24) + (v1 >> 24) + (v2 >> 24) + (v3 >> 24);
      res = a | (b << 16);
    } else if (fld == 3) {
      res = __float_as_uint(fminf(fminf(__uint_as_float(v0), __uint_as_float(v1)),
                                  fminf(__uint_as_float(v2), __uint_as_float(v3))));
    } else {
      res = __float_as_uint(__uint_as_float(v0) + __uint_as_float(v1) +
                            __uint_as_float(v2) + __uint_as_float(v3));
    }
    part[((size_t)(R + row) * 16 + cg) * 8 + fld] = res;
  }
}

// ---- kernel 3: per-row combine. 1 wave = 1 row: exact threshold from
// c1 + rank-sorted window; guard failures flagged for exact fallback. ----
__global__ __launch_bounds__(256) void nca_combine(
    const float* __restrict__ x, const unsigned* __restrict__ part,
    const uint2* __restrict__ winbuf, const int* __restrict__ wincnt,
    int* __restrict__ flag, float* __restrict__ row_loss, float* __restrict__ out) {
  __shared__ unsigned sk[4][64];
  __shared__ unsigned sk2[4][64];
  __shared__ unsigned ss2[4][64];

  const int tid = threadIdx.x, w = tid >> 6, lane = tid & 63;
  const int i = blockIdx.x * 4 + w;

  // f64 self-dot (decision sim[i][i] < 1.0)
  double sx0 = (double)x[(size_t)i * DD + lane];
  double sx1 = (double)x[(size_t)i * DD + lane + 64];
  const double selfd = wsum_d(sx0 * sx0 + sx1 * sx1);
  const bool self_pos = (selfd < 1.0);

  // gather 16 partials
  float base = 0.f, pes = 0.f, nes = 0.f, minp = __builtin_inff();
  float pos_s = 0.f, neg_s = 0.f;
  int c1 = 0, pc1 = 0, pos_c = 0, neg_c = 0;
  if (lane < 16) {
    const unsigned* p = &part[((size_t)i * 16 + lane) * 8];
    uint4 a = *reinterpret_cast<const uint4*>(p);
    uint4 b = *reinterpret_cast<const uint4*>(p + 4);
    base = __uint_as_float(a.x); pes = __uint_as_float(a.y);
    nes  = __uint_as_float(a.z); minp = __uint_as_float(a.w);
    c1 = b.x & 0xFFFF; pc1 = b.x >> 16;
    pos_s = __uint_as_float(b.y); neg_s = __uint_as_float(b.z);
    pos_c = b.w & 0xFFFF; neg_c = b.w >> 16;
  }
  base = wsum_f(base); pes = wsum_f(pes); nes = wsum_f(nes);
  minp = wmin_f(minp);
  c1 = wsum_i(c1); pc1 = wsum_i(pc1);
  pos_s = wsum_f(pos_s); neg_s = wsum_f(neg_s);
  pos_c = wsum_i(pos_c); neg_c = wsum_i(neg_c);

  const int wt = wincnt[i];
  const bool fast = (c1 <= KSEL) && (c1 + wt > KSEL) && (wt <= 64);
  if (!fast) {           // exact fallback will recompute this row
    if (lane == 0) { int p = atomicAdd(&flag[0], 1); flag[1 + p] = i; }
    return;
  }

  // rank-sort the <=64 window entries (deterministic: key order, lane tiebreak)
  unsigned key = 0xFFFFFFFFu, same = 0u;
  if (lane < wt) { uint2 e = winbuf[(size_t)i * 64 + lane]; key = e.x; same = e.y; }
  sk[w][lane] = key;
  int rank = 0;
  for (int m = 0; m < 64; ++m) {
    unsigned km = sk[w][m];
    rank += (km < key || (km == key && m < lane)) ? 1 : 0;
  }
  sk2[w][rank] = key; ss2[w][rank] = same;
  const unsigned thrkey = sk2[w][KSEL - c1];   // exact rank-KSEL key

  unsigned k2v = sk2[w][lane], sm2 = ss2[w][lane];
  float wp = 0.f, wn = 0.f; int hp = 0;
  if (lane < wt && k2v < thrkey) {
    float e = expf(-ALPHA_C * k2f(k2v));
    if (sm2) { wp += e; hp = 1; } else wn += e;
  }
  wp = wsum_f(wp); wn = wsum_f(wn); hp = wsum_i(hp);

  const float basem = base * (1.0f / NN);
  const float eb = expf(ALPHA_C * basem);      // exp(a(base-s)) = eb*exp(-a*s)
  const float minp2 = self_pos ? fminf(minp, (float)selfd) : minp;
  const bool haspos = (pc1 > 0) || (hp > 0);
  const float pl = haspos ? eb * (pes + wp) : expf(ALPHA_C * (basem - minp2));
  const float nl = eb * (nes + wn);
  if (lane == 0) row_loss[i] = -logf(pl / (pl + nl));

  if (i == NN - 1 && lane == 0) {              // diagnostics from last row
    float ps = pos_s + (self_pos ? (float)selfd : 0.f);
    int   pc = pos_c + (self_pos ? 1 : 0);
    out[2] = ps / (float)pc;
    out[3] = neg_s / (float)neg_c;
  }
}

// ---- kernel 4: exact fallback for flagged rows (f32 dots + binary search) ----
__global__ __launch_bounds__(256) void nca_fallback(
    const float* __restrict__ x, const int* __restrict__ tgt,
    const int* __restrict__ flag, float* __restrict__ row_loss,
    float* __restrict__ out) {
  __shared__ float xi[DD];
  __shared__ double redD[4];
  __shared__ int redI[2][4];
  __shared__ double redP[4], redN[4];
  __shared__ float redM[4];
  __shared__ int redH[4], redC[4], redC2[4];
  __shared__ unsigned cbuf[64];
  __shared__ int ccount;

  const int tid = threadIdx.x, w = tid >> 6, lane = tid & 63;
  const int nf = flag[0];
  for (int fi = blockIdx.x; fi < nf; fi += gridDim.x) {
    const int i = flag[1 + fi];
    const int ti = tgt[i];
    __syncthreads();
    if (tid < DD) xi[tid] = x[(size_t)i * DD + tid];
    __syncthreads();

    // sims: thread owns cols j = c*256 + tid
    float sims[16];
    const float4* xiv = reinterpret_cast<const float4*>(xi);
    for (int c = 0; c < 16; ++c) {
      const int j = (c << 8) + tid;
      const float4* xj = reinterpret_cast<const float4*>(x + (size_t)j * DD);
      float a0 = 0, a1 = 0, a2 = 0, a3 = 0;
      #pragma unroll
      for (int d = 0; d < 32; ++d) {
        float4 u = xiv[d]; float4 v = xj[d];
        a0 = fmaf(u.x, v.x, a0); a1 = fmaf(u.y, v.y, a1);
        a2 = fmaf(u.z, v.z, a2); a3 = fmaf(u.w, v.w, a3);
      }
      sims[c] = (a0 + a1) + (a2 + a3);
    }

    double sx0 = (double)xi[lane], sx1 = (double)xi[lane + 64];
    const double selfd = wsum_d(sx0 * sx0 + sx1 * sx1);
    const bool self_pos = (selfd < 1.0);

    unsigned kv[16];
    double bs = 0.0;
    #pragma unroll
    for (int c = 0; c < 16; ++c) { bs += (double)sims[c]; kv[c] = f2k(sims[c]); }
    if (!self_pos && ((i & 255) == tid)) kv[i >> 8] = 0xFFFFFFFFu;

    bs = wsum_d(bs);
    if (lane == 0) redD[w] = bs;
    __syncthreads();
    const float basef = (float)((redD[0] + redD[1] + redD[2] + redD[3]) * (1.0 / NN));

    // exact bitwise binary search (round-10 proven)
    unsigned lo = 0;
    int nLo = 0, nHi = NN, b = 31, par = 0;
    while (b >= 0 && (nHi - nLo) > 64) {
      unsigned mid = lo | (1u << b);
      int c = 0;
      #pragma unroll
      for (int t = 0; t < 16; ++t) c += (kv[t] < mid) ? 1 : 0;
      c = wsum_i(c);
      if (lane == 0) redI[par][w] = c;
      __syncthreads();
      c = redI[par][0] + redI[par][1] + redI[par][2] + redI[par][3];
      par ^= 1;
      if (c <= KSEL) { lo = mid; nLo = c; }
      else nHi = c;
      --b;
    }
    unsigned keysel;
    if ((nHi - nLo) <= 64) {
      const int shift = b + 1;
      const unsigned pfx = lo >> shift;
      if (tid == 0) ccount = 0;
      __syncthreads();
      #pragma unroll
      for (int t = 0; t < 16; ++t)
        if ((kv[t] >> shift) == pfx) { int p = atomicAdd(&ccount, 1); cbuf[p] = kv[t]; }
      __syncthreads();
      const int total = ccount;
      unsigned v = cbuf[lane];
      unsigned long long amask = (total >= 64) ? ~0ull : ((1ull << total) - 1ull);
      int ww = KSEL - nLo;
      for (int bb = b; bb >= 0; --bb) {
        unsigned long long z = __ballot(((amask >> lane) & 1ull) &&
                                        (((v >> bb) & 1u) == 0u));
        int zc = __popcll(z);
        if (ww < zc) amask = z;
        else { ww -= zc; amask &= ~z; }
      }
      int first = __ffsll((unsigned long long)amask) - 1;
      keysel = __shfl(v, first, 64);
    } else {
      keysel = lo;
    }
    const float thr = k2f(keysel);

    double psum = 0.0, nsum = 0.0;
    float minp = __builtin_inff();
    int hasp = 0;
    double pss = 0.0, nss = 0.0;
    int pct = 0, nct = 0;
    #pragma unroll
    for (int c = 0; c < 16; ++c) {
      const int j = (c << 8) + tid;
      const float s = k2f(kv[c]);   // NaN for excluded self
      const bool same = (tgt[j] == ti);
      const bool vpos = same && ((j == i) ? self_pos : (s < 1.0f));
      if (vpos) { minp = fminf(minp, s); pss += (double)s; pct++; }
      if (!same) { nss += (double)s; nct++; }
      if (s < thr) {
        float wgt = expf(ALPHA_C * (basef - s));
        if (vpos) { psum += (double)wgt; hasp = 1; }
        else if (!same) nsum += (double)wgt;
      }
    }
    psum = wsum_d(psum); nsum = wsum_d(nsum);
    minp = wmin_f(minp); hasp = wsum_i(hasp);
    if (lane == 0) { redP[w] = psum; redN[w] = nsum; redM[w] = minp; redH[w] = hasp; }
    __syncthreads();
    const double tpsum = redP[0] + redP[1] + redP[2] + redP[3];
    const double tnsum = redN[0] + redN[1] + redN[2] + redN[3];
    const float  tminp = fminf(fminf(redM[0], redM[1]), fminf(redM[2], redM[3]));
    const int    thasp = redH[0] + redH[1] + redH[2] + redH[3];

    if (i == NN - 1) {
      __syncthreads();
      pss = wsum_d(pss); nss = wsum_d(nss);
      pct = wsum_i(pct); nct = wsum_i(nct);
      if (lane == 0) { redP[w] = pss; redN[w] = nss; redC[w] = pct; redC2[w] = nct; }
      __syncthreads();
      if (tid == 0) {
        out[2] = (float)((redP[0] + redP[1] + redP[2] + redP[3]) /
                         (double)(redC[0] + redC[1] + redC[2] + redC[3]));
        out[3] = (float)((redN[0] + redN[1] + redN[2] + redN[3]) /
                         (double)(redC2[0] + redC2[1] + redC2[2] + redC2[3]));
      }
    }
    if (tid == 0) {
      float pl = (thasp > 0) ? (float)tpsum : expf(ALPHA_C * (basef - tminp));
      row_loss[i] = -logf(pl / (pl + (float)tnsum));
    }
  }
}

// ---- kernel 5: deterministic mean of per-row losses ----
__global__ void nca_final(const float* __restrict__ row_loss, float* __restrict__ out) {
  __shared__ double redd[4];
  int tid = threadIdx.x;
  double s = 0.0;
  for (int i = tid; i < NN; i += 256) s += (double)row_loss[i];
  #pragma unroll
  for (int m = 32; m; m >>= 1) s += __shfl_xor(s, m, 64);
  if ((tid & 63) == 0) redd[tid >> 6] = s;
  __syncthreads();
  if (tid == 0) {
    double tot = redd[0] + redd[1] + redd[2] + redd[3];
    out[0] = (float)(tot * (1.0 / NN));
    out[1] = 0.0f;
  }
}

extern "C" void kernel_launch(void* const* d_in, const int* in_sizes, int n_in,
                              void* d_out, int out_size, void* d_ws, size_t ws_size,
                              hipStream_t stream) {
  const float* x  = (const float*)d_in[0];
  const int* tgt  = (const int*)d_in[1];
  float* out      = (float*)d_out;

  // ws: xhi 1MB | xlo 1MB | row_loss 16KB | part 2MB | winbuf 2MB | wincnt 16KB | flag
  short* xhi      = (short*)d_ws;
  short* xlo      = xhi + (size_t)NN * DD;
  float* row_loss = (float*)(xlo + (size_t)NN * DD);
  unsigned* part  = (unsigned*)(row_loss + NN);
  uint2* winbuf   = (uint2*)(part + (size_t)NN * 16 * 8);
  int* wincnt     = (int*)(winbuf + (size_t)NN * 64);
  int* flag       = wincnt + NN;

  nca_prep<<<(NN * DD / 8) / 256, 256, 0, stream>>>(x, xhi, xlo, wincnt, flag);
  nca_gemm<<<(NN / 32) * (NN / 256), 256, 0, stream>>>(xhi, xlo, tgt, part, winbuf, wincnt);
  nca_combine<<<NN / 4, 256, 0, stream>>>(x, part, winbuf, wincnt, flag, row_loss, out);
  nca_fallback<<<64, 256, 0, stream>>>(x, tgt, flag, row_loss, out);
  nca_final<<<1, 256, 0, stream>>>(row_loss, out);
}

// Round 14
// 78.738 us; speedup vs baseline: 5.1878x; 5.1878x over previous
//
#include <hip/hip_runtime.h>
#include <math.h>

#define NN 4096
#define DD 128
#define ALPHA_C 16.0f
#define KSEL 32         // threshold = (K+1)-th smallest, 0-based index K
#define P1F -0.245f     // pivots bracketing rank-32 for N(0,1/128) sims
#define P2F -0.19f
#define WCAP 128        // window capacity per row (wt ~ 53 +- 7.3; 128 = +10 sigma)

typedef __attribute__((ext_vector_type(8))) short bf16x8;
typedef __attribute__((ext_vector_type(4))) float f32x4;

// ---- float <-> order-preserving u32 key ----
__device__ __forceinline__ unsigned f2k(float f) {
  unsigned b = __float_as_uint(f);
  return (b & 0x80000000u) ? ~b : (b | 0x80000000u);
}
__device__ __forceinline__ float k2f(unsigned k) {
  unsigned b = (k & 0x80000000u) ? (k & 0x7FFFFFFFu) : ~k;
  return __uint_as_float(b);
}

// ---- wave (64-lane) butterfly reductions ----
__device__ __forceinline__ double wsum_d(double v) {
  #pragma unroll
  for (int m = 32; m; m >>= 1) v += __shfl_xor(v, m, 64);
  return v;
}
__device__ __forceinline__ int wsum_i(int v) {
  #pragma unroll
  for (int m = 32; m; m >>= 1) v += __shfl_xor(v, m, 64);
  return v;
}
__device__ __forceinline__ float wsum_f(float v) {
  #pragma unroll
  for (int m = 32; m; m >>= 1) v += __shfl_xor(v, m, 64);
  return v;
}
__device__ __forceinline__ float wmin_f(float v) {
  #pragma unroll
  for (int m = 32; m; m >>= 1) v = fminf(v, __shfl_xor(v, m, 64));
  return v;
}

// ---- kernel 1: split x -> bf16 hi/lo fragment-major; zero counters ----
__global__ __launch_bounds__(256) void nca_prep(
    const float* __restrict__ x, short* __restrict__ xhi, short* __restrict__ xlo,
    int* __restrict__ wincnt, int* __restrict__ flag) {
  const int f  = blockIdx.x * blockDim.x + threadIdx.x;  // 0 .. N*D/8-1
  if (f < NN) wincnt[f] = 0;
  if (f == NN) flag[0] = 0;
  const int l  = f & 63;
  const int kb = (f >> 6) & 3;
  const int rg = f >> 8;
  const int row = (rg << 4) + (l & 15);
  const int k0  = (kb << 5) + ((l >> 4) << 3);
  const float* src = x + (size_t)row * DD + k0;
  float4 v0 = *reinterpret_cast<const float4*>(src);
  float4 v1 = *reinterpret_cast<const float4*>(src + 4);
  float vv[8] = {v0.x, v0.y, v0.z, v0.w, v1.x, v1.y, v1.z, v1.w};
  bf16x8 h, lo;
  #pragma unroll
  for (int q = 0; q < 8; ++q) {
    unsigned u  = __float_as_uint(vv[q]);
    unsigned hb = (u + 0x7FFFu + ((u >> 16) & 1u)) >> 16;
    float hf    = __uint_as_float(hb << 16);
    float lf    = vv[q] - hf;
    unsigned ul = __float_as_uint(lf);
    unsigned lb = (ul + 0x7FFFu + ((ul >> 16) & 1u)) >> 16;
    h[q] = (short)hb; lo[q] = (short)lb;
  }
  *reinterpret_cast<bf16x8*>(xhi + (size_t)f * 8) = h;
  *reinterpret_cast<bf16x8*>(xlo + (size_t)f * 8) = lo;
}

// ---- kernel 2: fused MFMA GEMM + selection epilogue (split-K partials) ----
// Per (row, colblock cg): 8-u32 partial record:
// 0 base f32 | 1 pes f32 | 2 nes f32 | 3 minp f32 | 4 c1|pc1<<16
// 5 pos_s f32 | 6 neg_s f32 | 7 pos_c|neg_c<<16. Self skipped except base.
// Window values (key in [P1,P2)) appended to winbuf[row][<WCAP] via atomics.
__global__ __launch_bounds__(256) void nca_gemm(
    const short* __restrict__ xhi, const short* __restrict__ xlo,
    const int* __restrict__ tgt, unsigned* __restrict__ part,
    uint2* __restrict__ winbuf, int* __restrict__ wincnt) {
  __shared__ unsigned state[4][32][8];   // 4 KB: per-wave per-row partials

  const int tid = threadIdx.x;
  const int w   = tid >> 6;
  const int l   = tid & 63;
  const int rg  = blockIdx.x >> 4;
  const int cg  = blockIdx.x & 15;
  const int R   = rg << 5;                 // 32 rows
  const int C   = (cg << 8) + (w << 6);    // 64 cols per wave
  const int rga = rg << 1;
  const int rgb = (cg << 4) + (w << 2);

  f32x4 acc[2][4];
  #pragma unroll
  for (int rt = 0; rt < 2; ++rt)
    #pragma unroll
    for (int t = 0; t < 4; ++t) acc[rt][t] = (f32x4){0.f, 0.f, 0.f, 0.f};

  #pragma unroll
  for (int kb = 0; kb < 4; ++kb) {
    bf16x8 ah[2], al[2], bh[4], bl[4];
    #pragma unroll
    for (int rt = 0; rt < 2; ++rt) {
      const size_t off = ((size_t)((rga + rt) * 4 + kb) * 64 + l) * 8;
      ah[rt] = *reinterpret_cast<const bf16x8*>(xhi + off);
      al[rt] = *reinterpret_cast<const bf16x8*>(xlo + off);
    }
    #pragma unroll
    for (int t = 0; t < 4; ++t) {
      const size_t off = ((size_t)((rgb + t) * 4 + kb) * 64 + l) * 8;
      bh[t] = *reinterpret_cast<const bf16x8*>(xhi + off);
      bl[t] = *reinterpret_cast<const bf16x8*>(xlo + off);
    }
    #pragma unroll
    for (int rt = 0; rt < 2; ++rt)
      #pragma unroll
      for (int t = 0; t < 4; ++t) {
        acc[rt][t] = __builtin_amdgcn_mfma_f32_16x16x32_bf16(ah[rt], bh[t], acc[rt][t], 0, 0, 0);
        acc[rt][t] = __builtin_amdgcn_mfma_f32_16x16x32_bf16(ah[rt], bl[t], acc[rt][t], 0, 0, 0);
        acc[rt][t] = __builtin_amdgcn_mfma_f32_16x16x32_bf16(al[rt], bh[t], acc[rt][t], 0, 0, 0);
      }
  }

  // ---- selection epilogue ----
  // C/D layout (m89-verified): col = lane&15, row = (lane>>4)*4 + reg
  const int rbase = (l >> 4) << 2;
  const int cc    = l & 15;
  const unsigned P1k = f2k(P1F), P2k = f2k(P2F);
  const bool diagblk = (R + 32 == NN);     // block containing row NN-1

  int tr[2][4], tc[4];
  #pragma unroll
  for (int rt = 0; rt < 2; ++rt)
    #pragma unroll
    for (int r = 0; r < 4; ++r) tr[rt][r] = tgt[R + (rt << 4) + rbase + r];
  #pragma unroll
  for (int t = 0; t < 4; ++t) tc[t] = tgt[C + (t << 4) + cc];

  #pragma unroll
  for (int rt = 0; rt < 2; ++rt) {
    #pragma unroll
    for (int r = 0; r < 4; ++r) {
      const int row_l = (rt << 4) + rbase + r;
      const int grow  = R + row_l;
      float base4 = 0.f, pes4 = 0.f, nes4 = 0.f, minp4 = __builtin_inff();
      float pos4 = 0.f, neg4 = 0.f;
      int cnts4 = 0;   // bytes: c1 | pc1<<8 | pos_c<<16 | neg_c<<24 (each <=4/lane)
      #pragma unroll
      for (int t = 0; t < 4; ++t) {
        const float s = acc[rt][t][r];
        const int j = C + (t << 4) + cc;
        base4 += s;                          // base includes self
        if (j != grow) {
          const bool same = (tc[t] == tr[rt][r]);
          const unsigned key = f2k(s);
          if (key < P1k) {                   // below lower pivot: accumulate
            const float e = expf(-ALPHA_C * s);
            cnts4 += 1;
            if (same) { pes4 += e; cnts4 += (1 << 8); }
            else nes4 += e;
          } else if (key < P2k) {            // window candidate
            int p = atomicAdd(&wincnt[grow], 1);
            if (p < WCAP) winbuf[(size_t)grow * WCAP + p] = make_uint2(key, same ? 1u : 0u);
          }
          if (same) {
            if (s < 1.0f) {
              minp4 = fminf(minp4, s);
              if (diagblk) { pos4 += s; cnts4 += (1 << 16); }
            }
          } else if (diagblk) { neg4 += s; cnts4 += (1 << 24); }
        }
      }
      // combine the 16 lanes sharing this row (xor masks stay in-quarter)
      #pragma unroll
      for (int m = 1; m < 16; m <<= 1) {
        base4 += __shfl_xor(base4, m, 64);
        pes4  += __shfl_xor(pes4,  m, 64);
        nes4  += __shfl_xor(nes4,  m, 64);
        minp4  = fminf(minp4, __shfl_xor(minp4, m, 64));
        cnts4 += __shfl_xor(cnts4, m, 64);
        if (diagblk) {
          pos4 += __shfl_xor(pos4, m, 64);
          neg4 += __shfl_xor(neg4, m, 64);
        }
      }
      if ((l & 15) == 0) {
        unsigned* st = &state[w][row_l][0];
        st[0] = __float_as_uint(base4); st[1] = __float_as_uint(pes4);
        st[2] = __float_as_uint(nes4);  st[3] = __float_as_uint(minp4);
        st[4] = (unsigned)cnts4;        st[5] = __float_as_uint(pos4);
        st[6] = __float_as_uint(neg4);  st[7] = (unsigned)cnts4;
      }
    }
  }
  __syncthreads();

  // cross-wave combine: thread -> (row, field); widen packed counts to u16
  {
    const int row = tid >> 3, fld = tid & 7;
    unsigned v0 = state[0][row][fld], v1 = state[1][row][fld];
    unsigned v2 = state[2][row][fld], v3 = state[3][row][fld];
    unsigned res;
    if (fld == 4) {
      unsigned a = (v0 & 255) + (v1 & 255) + (v2 & 255) + (v3 & 255);
      unsigned b = ((v0 >> 8) & 255) + ((v1 >> 8) & 255) + ((v2 >> 8) & 255) + ((v3 >> 8) & 255);
      res = a | (b << 16);
    } else if (fld == 7) {
      unsigned a = ((v0 >> 16) & 255) + ((v1 >> 16) & 255) + ((v2 >> 16) & 255) + ((v3 >> 16) & 255);
      unsigned b = (v0 >> 24) + (v1 >> 24) + (v2 >> 24) + (v3 >> 24);
      res = a | (b << 16);
    } else if (fld == 3) {
      res = __float_as_uint(fminf(fminf(__uint_as_float(v0), __uint_as_float(v1)),
                                  fminf(__uint_as_float(v2), __uint_as_float(v3))));
    } else {
      res = __float_as_uint(__uint_as_float(v0) + __uint_as_float(v1) +
                            __uint_as_float(v2) + __uint_as_float(v3));
    }
    part[((size_t)(R + row) * 16 + cg) * 8 + fld] = res;
  }
}

// ---- kernel 3: per-row combine. 1 wave = 1 row. Exact threshold =
// rank-(KSEL-c1) window key via wave-local 32-round ballot descend
// (2 keys/lane, no barriers). Guard failures flagged for exact fallback. ----
__global__ __launch_bounds__(256) void nca_combine(
    const float* __restrict__ x, const unsigned* __restrict__ part,
    const uint2* __restrict__ winbuf, const int* __restrict__ wincnt,
    int* __restrict__ flag, float* __restrict__ row_loss, float* __restrict__ out) {
  const int tid = threadIdx.x, w = tid >> 6, lane = tid & 63;
  const int i = blockIdx.x * 4 + w;

  // f64 self-dot (decision sim[i][i] < 1.0)
  double sx0 = (double)x[(size_t)i * DD + lane];
  double sx1 = (double)x[(size_t)i * DD + lane + 64];
  const double selfd = wsum_d(sx0 * sx0 + sx1 * sx1);
  const bool self_pos = (selfd < 1.0);

  // gather 16 partials
  float base = 0.f, pes = 0.f, nes = 0.f, minp = __builtin_inff();
  float pos_s = 0.f, neg_s = 0.f;
  int c1 = 0, pc1 = 0, pos_c = 0, neg_c = 0;
  if (lane < 16) {
    const unsigned* p = &part[((size_t)i * 16 + lane) * 8];
    uint4 a = *reinterpret_cast<const uint4*>(p);
    uint4 b = *reinterpret_cast<const uint4*>(p + 4);
    base = __uint_as_float(a.x); pes = __uint_as_float(a.y);
    nes  = __uint_as_float(a.z); minp = __uint_as_float(a.w);
    c1 = b.x & 0xFFFF; pc1 = b.x >> 16;
    pos_s = __uint_as_float(b.y); neg_s = __uint_as_float(b.z);
    pos_c = b.w & 0xFFFF; neg_c = b.w >> 16;
  }
  base = wsum_f(base); pes = wsum_f(pes); nes = wsum_f(nes);
  minp = wmin_f(minp);
  c1 = wsum_i(c1); pc1 = wsum_i(pc1);
  pos_s = wsum_f(pos_s); neg_s = wsum_f(neg_s);
  pos_c = wsum_i(pos_c); neg_c = wsum_i(neg_c);

  const int wt = wincnt[i];
  const bool fast = (c1 <= KSEL) && (c1 + wt > KSEL) && (wt <= WCAP);
  if (!fast) {           // exact fallback will recompute this row
    if (lane == 0) { int p = atomicAdd(&flag[0], 1); flag[1 + p] = i; }
    return;
  }

  // load 2 window entries per lane (invalid -> max key, never selected)
  unsigned k0 = 0xFFFFFFFFu, k1 = 0xFFFFFFFFu, s0 = 0u, s1 = 0u;
  if (lane < wt) { uint2 e = winbuf[(size_t)i * WCAP + lane]; k0 = e.x; s0 = e.y; }
  if (lane + 64 < wt) { uint2 e = winbuf[(size_t)i * WCAP + 64 + lane]; k1 = e.x; s1 = e.y; }

  // rank-r window key: max u with count(keys < u) <= r (round-2-verified)
  const int r = KSEL - c1;               // 0 <= r < wt by guard
  unsigned thrkey = 0;
  for (int b = 31; b >= 0; --b) {
    unsigned mid = thrkey | (1u << b);
    int c = (int)__popcll(__ballot(k0 < mid)) + (int)__popcll(__ballot(k1 < mid));
    if (c <= r) thrkey = mid;
  }

  float wp = 0.f, wn = 0.f; int hp = 0;
  if (k0 < thrkey) {
    float e = expf(-ALPHA_C * k2f(k0));
    if (s0) { wp += e; hp = 1; } else wn += e;
  }
  if (k1 < thrkey) {
    float e = expf(-ALPHA_C * k2f(k1));
    if (s1) { wp += e; hp = 1; } else wn += e;
  }
  wp = wsum_f(wp); wn = wsum_f(wn); hp = wsum_i(hp);

  const float basem = base * (1.0f / NN);
  const float eb = expf(ALPHA_C * basem);      // exp(a(base-s)) = eb*exp(-a*s)
  const float minp2 = self_pos ? fminf(minp, (float)selfd) : minp;
  const bool haspos = (pc1 > 0) || (hp > 0);
  const float pl = haspos ? eb * (pes + wp) : expf(ALPHA_C * (basem - minp2));
  const float nl = eb * (nes + wn);
  if (lane == 0) row_loss[i] = -logf(pl / (pl + nl));

  if (i == NN - 1 && lane == 0) {              // diagnostics from last row
    float ps = pos_s + (self_pos ? (float)selfd : 0.f);
    int   pc = pos_c + (self_pos ? 1 : 0);
    out[2] = ps / (float)pc;
    out[3] = neg_s / (float)neg_c;
  }
}

// ---- kernel 4: exact fallback, 1 block per flagged row (early exit) ----
__global__ __launch_bounds__(256) void nca_fallback(
    const float* __restrict__ x, const int* __restrict__ tgt,
    const int* __restrict__ flag, float* __restrict__ row_loss,
    float* __restrict__ out) {
  __shared__ float xi[DD];
  __shared__ double redD[4];
  __shared__ int redI[2][4];
  __shared__ double redP[4], redN[4];
  __shared__ float redM[4];
  __shared__ int redH[4], redC[4], redC2[4];
  __shared__ unsigned cbuf[64];
  __shared__ int ccount;

  const int nf = flag[0];
  if (blockIdx.x >= nf) return;
  const int tid = threadIdx.x, w = tid >> 6, lane = tid & 63;
  const int i = flag[1 + blockIdx.x];
  const int ti = tgt[i];
  if (tid < DD) xi[tid] = x[(size_t)i * DD + tid];
  __syncthreads();

  // sims: thread owns cols j = c*256 + tid
  float sims[16];
  const float4* xiv = reinterpret_cast<const float4*>(xi);
  for (int c = 0; c < 16; ++c) {
    const int j = (c << 8) + tid;
    const float4* xj = reinterpret_cast<const float4*>(x + (size_t)j * DD);
    float a0 = 0, a1 = 0, a2 = 0, a3 = 0;
    #pragma unroll
    for (int d = 0; d < 32; ++d) {
      float4 u = xiv[d]; float4 v = xj[d];
      a0 = fmaf(u.x, v.x, a0); a1 = fmaf(u.y, v.y, a1);
      a2 = fmaf(u.z, v.z, a2); a3 = fmaf(u.w, v.w, a3);
    }
    sims[c] = (a0 + a1) + (a2 + a3);
  }

  double sx0 = (double)xi[lane], sx1 = (double)xi[lane + 64];
  const double selfd = wsum_d(sx0 * sx0 + sx1 * sx1);
  const bool self_pos = (selfd < 1.0);

  unsigned kv[16];
  double bs = 0.0;
  #pragma unroll
  for (int c = 0; c < 16; ++c) { bs += (double)sims[c]; kv[c] = f2k(sims[c]); }
  if (!self_pos && ((i & 255) == tid)) kv[i >> 8] = 0xFFFFFFFFu;

  bs = wsum_d(bs);
  if (lane == 0) redD[w] = bs;
  __syncthreads();
  const float basef = (float)((redD[0] + redD[1] + redD[2] + redD[3]) * (1.0 / NN));

  // exact bitwise binary search (round-10 proven)
  unsigned lo = 0;
  int nLo = 0, nHi = NN, b = 31, par = 0;
  while (b >= 0 && (nHi - nLo) > 64) {
    unsigned mid = lo | (1u << b);
    int c = 0;
    #pragma unroll
    for (int t = 0; t < 16; ++t) c += (kv[t] < mid) ? 1 : 0;
    c = wsum_i(c);
    if (lane == 0) redI[par][w] = c;
    __syncthreads();
    c = redI[par][0] + redI[par][1] + redI[par][2] + redI[par][3];
    par ^= 1;
    if (c <= KSEL) { lo = mid; nLo = c; }
    else nHi = c;
    --b;
  }
  unsigned keysel;
  if ((nHi - nLo) <= 64) {
    const int shift = b + 1;
    const unsigned pfx = lo >> shift;
    if (tid == 0) ccount = 0;
    __syncthreads();
    #pragma unroll
    for (int t = 0; t < 16; ++t)
      if ((kv[t] >> shift) == pfx) { int p = atomicAdd(&ccount, 1); cbuf[p] = kv[t]; }
    __syncthreads();
    const int total = ccount;
    unsigned v = cbuf[lane];
    unsigned long long amask = (total >= 64) ? ~0ull : ((1ull << total) - 1ull);
    int ww = KSEL - nLo;
    for (int bb = b; bb >= 0; --bb) {
      unsigned long long z = __ballot(((amask >> lane) & 1ull) &&
                                      (((v >> bb) & 1u) == 0u));
      int zc = __popcll(z);
      if (ww < zc) amask = z;
      else { ww -= zc; amask &= ~z; }
    }
    int first = __ffsll((unsigned long long)amask) - 1;
    keysel = __shfl(v, first, 64);
  } else {
    keysel = lo;
  }
  const float thr = k2f(keysel);

  double psum = 0.0, nsum = 0.0;
  float minp = __builtin_inff();
  int hasp = 0;
  double pss = 0.0, nss = 0.0;
  int pct = 0, nct = 0;
  #pragma unroll
  for (int c = 0; c < 16; ++c) {
    const int j = (c << 8) + tid;
    const float s = k2f(kv[c]);   // NaN for excluded self
    const bool same = (tgt[j] == ti);
    const bool vpos = same && ((j == i) ? self_pos : (s < 1.0f));
    if (vpos) { minp = fminf(minp, s); pss += (double)s; pct++; }
    if (!same) { nss += (double)s; nct++; }
    if (s < thr) {
      float wgt = expf(ALPHA_C * (basef - s));
      if (vpos) { psum += (double)wgt; hasp = 1; }
      else if (!same) nsum += (double)wgt;
    }
  }
  psum = wsum_d(psum); nsum = wsum_d(nsum);
  minp = wmin_f(minp); hasp = wsum_i(hasp);
  if (lane == 0) { redP[w] = psum; redN[w] = nsum; redM[w] = minp; redH[w] = hasp; }
  __syncthreads();
  const double tpsum = redP[0] + redP[1] + redP[2] + redP[3];
  const double tnsum = redN[0] + redN[1] + redN[2] + redN[3];
  const float  tminp = fminf(fminf(redM[0], redM[1]), fminf(redM[2], redM[3]));
  const int    thasp = redH[0] + redH[1] + redH[2] + redH[3];

  if (i == NN - 1) {
    __syncthreads();
    pss = wsum_d(pss); nss = wsum_d(nss);
    pct = wsum_i(pct); nct = wsum_i(nct);
    if (lane == 0) { redP[w] = pss; redN[w] = nss; redC[w] = pct; redC2[w] = nct; }
    __syncthreads();
    if (tid == 0) {
      out[2] = (float)((redP[0] + redP[1] + redP[2] + redP[3]) /
                       (double)(redC[0] + redC[1] + redC[2] + redC[3]));
      out[3] = (float)((redN[0] + redN[1] + redN[2] + redN[3]) /
                       (double)(redC2[0] + redC2[1] + redC2[2] + redC2[3]));
    }
  }
  if (tid == 0) {
    float pl = (thasp > 0) ? (float)tpsum : expf(ALPHA_C * (basef - tminp));
    row_loss[i] = -logf(pl / (pl + (float)tnsum));
  }
}

// ---- kernel 5: deterministic mean of per-row losses ----
__global__ void nca_final(const float* __restrict__ row_loss, float* __restrict__ out) {
  __shared__ double redd[4];
  int tid = threadIdx.x;
  double s = 0.0;
  for (int i = tid; i < NN; i += 256) s += (double)row_loss[i];
  #pragma unroll
  for (int m = 32; m; m >>= 1) s += __shfl_xor(s, m, 64);
  if ((tid & 63) == 0) redd[tid >> 6] = s;
  __syncthreads();
  if (tid == 0) {
    double tot = redd[0] + redd[1] + redd[2] + redd[3];
    out[0] = (float)(tot * (1.0 / NN));
    out[1] = 0.0f;
  }
}

extern "C" void kernel_launch(void* const* d_in, const int* in_sizes, int n_in,
                              void* d_out, int out_size, void* d_ws, size_t ws_size,
                              hipStream_t stream) {
  const float* x  = (const float*)d_in[0];
  const int* tgt  = (const int*)d_in[1];
  float* out      = (float*)d_out;

  // ws: xhi 1MB | xlo 1MB | row_loss 16KB | part 2MB | winbuf 4MB | wincnt | flag
  short* xhi      = (short*)d_ws;
  short* xlo      = xhi + (size_t)NN * DD;
  float* row_loss = (float*)(xlo + (size_t)NN * DD);
  unsigned* part  = (unsigned*)(row_loss + NN);
  uint2* winbuf   = (uint2*)(part + (size_t)NN * 16 * 8);
  int* wincnt     = (int*)(winbuf + (size_t)NN * WCAP);
  int* flag       = wincnt + NN;

  nca_prep<<<(NN * DD / 8) / 256, 256, 0, stream>>>(x, xhi, xlo, wincnt, flag);
  nca_gemm<<<(NN / 32) * (NN / 256), 256, 0, stream>>>(xhi, xlo, tgt, part, winbuf, wincnt);
  nca_combine<<<NN / 4, 256, 0, stream>>>(x, part, winbuf, wincnt, flag, row_loss, out);
  nca_fallback<<<NN, 256, 0, stream>>>(x, tgt, flag, row_loss, out);
  nca_final<<<1, 256, 0, stream>>>(row_loss, out);
}

// Round 15
// 77.864 us; speedup vs baseline: 5.2461x; 1.0112x over previous
//
#include <hip/hip_runtime.h>
#include <math.h>

#define NN 4096
#define DD 128
#define ALPHA_C 16.0f
#define KSEL 32         // threshold = (K+1)-th smallest, 0-based index K
#define P1F -0.245f     // pivots bracketing rank-32 for N(0,1/128) sims
#define P2F -0.19f
#define WCAP 128        // window capacity per row (wt ~ 53 +- 7.3; 128 = +10 sigma)

typedef __attribute__((ext_vector_type(8))) short bf16x8;
typedef __attribute__((ext_vector_type(4))) float f32x4;

// ---- float <-> order-preserving u32 key ----
__device__ __forceinline__ unsigned f2k(float f) {
  unsigned b = __float_as_uint(f);
  return (b & 0x80000000u) ? ~b : (b | 0x80000000u);
}
__device__ __forceinline__ float k2f(unsigned k) {
  unsigned b = (k & 0x80000000u) ? (k & 0x7FFFFFFFu) : ~k;
  return __uint_as_float(b);
}

// ---- wave (64-lane) butterfly reductions ----
__device__ __forceinline__ double wsum_d(double v) {
  #pragma unroll
  for (int m = 32; m; m >>= 1) v += __shfl_xor(v, m, 64);
  return v;
}
__device__ __forceinline__ int wsum_i(int v) {
  #pragma unroll
  for (int m = 32; m; m >>= 1) v += __shfl_xor(v, m, 64);
  return v;
}
__device__ __forceinline__ float wsum_f(float v) {
  #pragma unroll
  for (int m = 32; m; m >>= 1) v += __shfl_xor(v, m, 64);
  return v;
}
__device__ __forceinline__ float wmin_f(float v) {
  #pragma unroll
  for (int m = 32; m; m >>= 1) v = fminf(v, __shfl_xor(v, m, 64));
  return v;
}

// ---- kernel 1: split x -> bf16 hi/lo fragment-major; zero counters ----
__global__ __launch_bounds__(256) void nca_prep(
    const float* __restrict__ x, short* __restrict__ xhi, short* __restrict__ xlo,
    int* __restrict__ wincnt, int* __restrict__ flag) {
  const int f  = blockIdx.x * blockDim.x + threadIdx.x;  // 0 .. N*D/8-1
  if (f < NN) wincnt[f] = 0;
  if (f == NN) flag[0] = 0;
  const int l  = f & 63;
  const int kb = (f >> 6) & 3;
  const int rg = f >> 8;
  const int row = (rg << 4) + (l & 15);
  const int k0  = (kb << 5) + ((l >> 4) << 3);
  const float* src = x + (size_t)row * DD + k0;
  float4 v0 = *reinterpret_cast<const float4*>(src);
  float4 v1 = *reinterpret_cast<const float4*>(src + 4);
  float vv[8] = {v0.x, v0.y, v0.z, v0.w, v1.x, v1.y, v1.z, v1.w};
  bf16x8 h, lo;
  #pragma unroll
  for (int q = 0; q < 8; ++q) {
    unsigned u  = __float_as_uint(vv[q]);
    unsigned hb = (u + 0x7FFFu + ((u >> 16) & 1u)) >> 16;
    float hf    = __uint_as_float(hb << 16);
    float lf    = vv[q] - hf;
    unsigned ul = __float_as_uint(lf);
    unsigned lb = (ul + 0x7FFFu + ((ul >> 16) & 1u)) >> 16;
    h[q] = (short)hb; lo[q] = (short)lb;
  }
  *reinterpret_cast<bf16x8*>(xhi + (size_t)f * 8) = h;
  *reinterpret_cast<bf16x8*>(xlo + (size_t)f * 8) = lo;
}

// ---- kernel 2: fused MFMA GEMM + BRANCHLESS selection epilogue ----
// Per (row, colblock cg): 8-u32 partial record:
// 0 base f32 | 1 pes f32 | 2 nes f32 | 3 minp f32 | 4 c1|pc1<<16
// 5 pos_s f32 | 6 neg_s f32 | 7 pos_c|neg_c<<16. Self skipped except base.
// Window values (key in [P1,P2)) appended to winbuf[row][<WCAP] via atomics
// behind a wave-uniform ballot guard.
__global__ __launch_bounds__(256) void nca_gemm(
    const short* __restrict__ xhi, const short* __restrict__ xlo,
    const int* __restrict__ tgt, unsigned* __restrict__ part,
    uint2* __restrict__ winbuf, int* __restrict__ wincnt) {
  __shared__ unsigned state[4][32][8];   // 4 KB: per-wave per-row partials

  const int tid = threadIdx.x;
  const int w   = tid >> 6;
  const int l   = tid & 63;
  const int rg  = blockIdx.x >> 4;
  const int cg  = blockIdx.x & 15;
  const int R   = rg << 5;                 // 32 rows
  const int C   = (cg << 8) + (w << 6);    // 64 cols per wave
  const int rga = rg << 1;
  const int rgb = (cg << 4) + (w << 2);

  f32x4 acc[2][4];
  #pragma unroll
  for (int rt = 0; rt < 2; ++rt)
    #pragma unroll
    for (int t = 0; t < 4; ++t) acc[rt][t] = (f32x4){0.f, 0.f, 0.f, 0.f};

  #pragma unroll
  for (int kb = 0; kb < 4; ++kb) {
    bf16x8 ah[2], al[2], bh[4], bl[4];
    #pragma unroll
    for (int rt = 0; rt < 2; ++rt) {
      const size_t off = ((size_t)((rga + rt) * 4 + kb) * 64 + l) * 8;
      ah[rt] = *reinterpret_cast<const bf16x8*>(xhi + off);
      al[rt] = *reinterpret_cast<const bf16x8*>(xlo + off);
    }
    #pragma unroll
    for (int t = 0; t < 4; ++t) {
      const size_t off = ((size_t)((rgb + t) * 4 + kb) * 64 + l) * 8;
      bh[t] = *reinterpret_cast<const bf16x8*>(xhi + off);
      bl[t] = *reinterpret_cast<const bf16x8*>(xlo + off);
    }
    #pragma unroll
    for (int rt = 0; rt < 2; ++rt)
      #pragma unroll
      for (int t = 0; t < 4; ++t) {
        acc[rt][t] = __builtin_amdgcn_mfma_f32_16x16x32_bf16(ah[rt], bh[t], acc[rt][t], 0, 0, 0);
        acc[rt][t] = __builtin_amdgcn_mfma_f32_16x16x32_bf16(ah[rt], bl[t], acc[rt][t], 0, 0, 0);
        acc[rt][t] = __builtin_amdgcn_mfma_f32_16x16x32_bf16(al[rt], bh[t], acc[rt][t], 0, 0, 0);
      }
  }

  // ---- selection epilogue (branchless except rare window append) ----
  // C/D layout (m89-verified): col = lane&15, row = (lane>>4)*4 + reg
  const int rbase = (l >> 4) << 2;
  const int cc    = l & 15;
  const unsigned P1k = f2k(P1F), P2k = f2k(P2F);
  const bool diagblk = (R + 32 == NN);     // block containing row NN-1

  int tr[2][4], tc[4];
  #pragma unroll
  for (int rt = 0; rt < 2; ++rt)
    #pragma unroll
    for (int r = 0; r < 4; ++r) tr[rt][r] = tgt[R + (rt << 4) + rbase + r];
  #pragma unroll
  for (int t = 0; t < 4; ++t) tc[t] = tgt[C + (t << 4) + cc];

  #pragma unroll
  for (int rt = 0; rt < 2; ++rt) {
    #pragma unroll
    for (int r = 0; r < 4; ++r) {
      const int row_l = (rt << 4) + rbase + r;
      const int grow  = R + row_l;
      float base4 = 0.f, pes4 = 0.f, nes4 = 0.f, minp4 = __builtin_inff();
      float pos4 = 0.f, neg4 = 0.f;
      int cnts4 = 0;   // bytes: c1 | pc1<<8 | pos_c<<16 | neg_c<<24 (each <=4/lane)
      #pragma unroll
      for (int t = 0; t < 4; ++t) {
        const float s = acc[rt][t][r];
        const int j = C + (t << 4) + cc;
        const bool same  = (tc[t] == tr[rt][r]);
        const bool nself = (j != grow);
        const unsigned key = f2k(s);
        base4 += s;                            // base includes self
        const float e = __expf(-ALPHA_C * s);  // always: v_exp path, no branch
        const bool below = nself && (key < P1k);
        pes4 += (below && same)  ? e : 0.f;
        nes4 += (below && !same) ? e : 0.f;
        cnts4 += below ? 1 : 0;
        cnts4 += (below && same) ? (1 << 8) : 0;
        const bool vp = nself && same && (s < 1.0f);
        minp4 = vp ? fminf(minp4, s) : minp4;
        if (diagblk) {                         // block-uniform branch
          pos4 += vp ? s : 0.f;
          cnts4 += vp ? (1 << 16) : 0;
          neg4 += (!same) ? s : 0.f;
          cnts4 += (!same) ? (1 << 24) : 0;
        }
        const bool inwin = nself && (key >= P1k) && (key < P2k);
        if (__ballot(inwin)) {                 // wave-uniform guard (rarely true)
          if (inwin) {
            int p = atomicAdd(&wincnt[grow], 1);
            if (p < WCAP) winbuf[(size_t)grow * WCAP + p] = make_uint2(key, same ? 1u : 0u);
          }
        }
      }
      // combine the 16 lanes sharing this row (xor masks stay in-quarter)
      #pragma unroll
      for (int m = 1; m < 16; m <<= 1) {
        base4 += __shfl_xor(base4, m, 64);
        pes4  += __shfl_xor(pes4,  m, 64);
        nes4  += __shfl_xor(nes4,  m, 64);
        minp4  = fminf(minp4, __shfl_xor(minp4, m, 64));
        cnts4 += __shfl_xor(cnts4, m, 64);
        if (diagblk) {
          pos4 += __shfl_xor(pos4, m, 64);
          neg4 += __shfl_xor(neg4, m, 64);
        }
      }
      if ((l & 15) == 0) {
        unsigned* st = &state[w][row_l][0];
        st[0] = __float_as_uint(base4); st[1] = __float_as_uint(pes4);
        st[2] = __float_as_uint(nes4);  st[3] = __float_as_uint(minp4);
        st[4] = (unsigned)cnts4;        st[5] = __float_as_uint(pos4);
        st[6] = __float_as_uint(neg4);  st[7] = (unsigned)cnts4;
      }
    }
  }
  __syncthreads();

  // cross-wave combine: thread -> (row, field); widen packed counts to u16
  {
    const int row = tid >> 3, fld = tid & 7;
    unsigned v0 = state[0][row][fld], v1 = state[1][row][fld];
    unsigned v2 = state[2][row][fld], v3 = state[3][row][fld];
    unsigned res;
    if (fld == 4) {
      unsigned a = (v0 & 255) + (v1 & 255) + (v2 & 255) + (v3 & 255);
      unsigned b = ((v0 >> 8) & 255) + ((v1 >> 8) & 255) + ((v2 >> 8) & 255) + ((v3 >> 8) & 255);
      res = a | (b << 16);
    } else if (fld == 7) {
      unsigned a = ((v0 >> 16) & 255) + ((v1 >> 16) & 255) + ((v2 >> 16) & 255) + ((v3 >> 16) & 255);
      unsigned b = (v0 >> 24) + (v1 >> 24) + (v2 >> 24) + (v3 >> 24);
      res = a | (b << 16);
    } else if (fld == 3) {
      res = __float_as_uint(fminf(fminf(__uint_as_float(v0), __uint_as_float(v1)),
                                  fminf(__uint_as_float(v2), __uint_as_float(v3))));
    } else {
      res = __float_as_uint(__uint_as_float(v0) + __uint_as_float(v1) +
                            __uint_as_float(v2) + __uint_as_float(v3));
    }
    part[((size_t)(R + row) * 16 + cg) * 8 + fld] = res;
  }
}

// ---- kernel 3: per-row combine. 1 wave = 1 row. Exact threshold =
// rank-(KSEL-c1) window key via wave-local 32-round ballot descend. ----
__global__ __launch_bounds__(256) void nca_combine(
    const float* __restrict__ x, const unsigned* __restrict__ part,
    const uint2* __restrict__ winbuf, const int* __restrict__ wincnt,
    int* __restrict__ flag, float* __restrict__ row_loss, float* __restrict__ out) {
  const int tid = threadIdx.x, w = tid >> 6, lane = tid & 63;
  const int i = blockIdx.x * 4 + w;

  // f64 self-dot (decision sim[i][i] < 1.0)
  double sx0 = (double)x[(size_t)i * DD + lane];
  double sx1 = (double)x[(size_t)i * DD + lane + 64];
  const double selfd = wsum_d(sx0 * sx0 + sx1 * sx1);
  const bool self_pos = (selfd < 1.0);

  // gather 16 partials
  float base = 0.f, pes = 0.f, nes = 0.f, minp = __builtin_inff();
  float pos_s = 0.f, neg_s = 0.f;
  int c1 = 0, pc1 = 0, pos_c = 0, neg_c = 0;
  if (lane < 16) {
    const unsigned* p = &part[((size_t)i * 16 + lane) * 8];
    uint4 a = *reinterpret_cast<const uint4*>(p);
    uint4 b = *reinterpret_cast<const uint4*>(p + 4);
    base = __uint_as_float(a.x); pes = __uint_as_float(a.y);
    nes  = __uint_as_float(a.z); minp = __uint_as_float(a.w);
    c1 = b.x & 0xFFFF; pc1 = b.x >> 16;
    pos_s = __uint_as_float(b.y); neg_s = __uint_as_float(b.z);
    pos_c = b.w & 0xFFFF; neg_c = b.w >> 16;
  }
  base = wsum_f(base); pes = wsum_f(pes); nes = wsum_f(nes);
  minp = wmin_f(minp);
  c1 = wsum_i(c1); pc1 = wsum_i(pc1);
  pos_s = wsum_f(pos_s); neg_s = wsum_f(neg_s);
  pos_c = wsum_i(pos_c); neg_c = wsum_i(neg_c);

  const int wt = wincnt[i];
  const bool fast = (c1 <= KSEL) && (c1 + wt > KSEL) && (wt <= WCAP);
  if (!fast) {           // exact fallback will recompute this row
    if (lane == 0) { int p = atomicAdd(&flag[0], 1); flag[1 + p] = i; }
    return;
  }

  // load 2 window entries per lane (invalid -> max key, never selected)
  unsigned k0 = 0xFFFFFFFFu, k1 = 0xFFFFFFFFu, s0 = 0u, s1 = 0u;
  if (lane < wt) { uint2 e = winbuf[(size_t)i * WCAP + lane]; k0 = e.x; s0 = e.y; }
  if (lane + 64 < wt) { uint2 e = winbuf[(size_t)i * WCAP + 64 + lane]; k1 = e.x; s1 = e.y; }

  // rank-r window key: max u with count(keys < u) <= r (round-2-verified)
  const int r = KSEL - c1;               // 0 <= r < wt by guard
  unsigned thrkey = 0;
  for (int b = 31; b >= 0; --b) {
    unsigned mid = thrkey | (1u << b);
    int c = (int)__popcll(__ballot(k0 < mid)) + (int)__popcll(__ballot(k1 < mid));
    if (c <= r) thrkey = mid;
  }

  float wp = 0.f, wn = 0.f; int hp = 0;
  if (k0 < thrkey) {
    float e = expf(-ALPHA_C * k2f(k0));
    if (s0) { wp += e; hp = 1; } else wn += e;
  }
  if (k1 < thrkey) {
    float e = expf(-ALPHA_C * k2f(k1));
    if (s1) { wp += e; hp = 1; } else wn += e;
  }
  wp = wsum_f(wp); wn = wsum_f(wn); hp = wsum_i(hp);

  const float basem = base * (1.0f / NN);
  const float eb = expf(ALPHA_C * basem);      // exp(a(base-s)) = eb*exp(-a*s)
  const float minp2 = self_pos ? fminf(minp, (float)selfd) : minp;
  const bool haspos = (pc1 > 0) || (hp > 0);
  const float pl = haspos ? eb * (pes + wp) : expf(ALPHA_C * (basem - minp2));
  const float nl = eb * (nes + wn);
  if (lane == 0) row_loss[i] = -logf(pl / (pl + nl));

  if (i == NN - 1 && lane == 0) {              // diagnostics from last row
    float ps = pos_s + (self_pos ? (float)selfd : 0.f);
    int   pc = pos_c + (self_pos ? 1 : 0);
    out[2] = ps / (float)pc;
    out[3] = neg_s / (float)neg_c;
  }
}

// ---- kernel 4: exact fallback, 1 block per flagged row (early exit) ----
__global__ __launch_bounds__(256) void nca_fallback(
    const float* __restrict__ x, const int* __restrict__ tgt,
    const int* __restrict__ flag, float* __restrict__ row_loss,
    float* __restrict__ out) {
  __shared__ float xi[DD];
  __shared__ double redD[4];
  __shared__ int redI[2][4];
  __shared__ double redP[4], redN[4];
  __shared__ float redM[4];
  __shared__ int redH[4], redC[4], redC2[4];
  __shared__ unsigned cbuf[64];
  __shared__ int ccount;

  const int nf = flag[0];
  if (blockIdx.x >= nf) return;
  const int tid = threadIdx.x, w = tid >> 6, lane = tid & 63;
  const int i = flag[1 + blockIdx.x];
  const int ti = tgt[i];
  if (tid < DD) xi[tid] = x[(size_t)i * DD + tid];
  __syncthreads();

  // sims: thread owns cols j = c*256 + tid
  float sims[16];
  const float4* xiv = reinterpret_cast<const float4*>(xi);
  for (int c = 0; c < 16; ++c) {
    const int j = (c << 8) + tid;
    const float4* xj = reinterpret_cast<const float4*>(x + (size_t)j * DD);
    float a0 = 0, a1 = 0, a2 = 0, a3 = 0;
    #pragma unroll
    for (int d = 0; d < 32; ++d) {
      float4 u = xiv[d]; float4 v = xj[d];
      a0 = fmaf(u.x, v.x, a0); a1 = fmaf(u.y, v.y, a1);
      a2 = fmaf(u.z, v.z, a2); a3 = fmaf(u.w, v.w, a3);
    }
    sims[c] = (a0 + a1) + (a2 + a3);
  }

  double sx0 = (double)xi[lane], sx1 = (double)xi[lane + 64];
  const double selfd = wsum_d(sx0 * sx0 + sx1 * sx1);
  const bool self_pos = (selfd < 1.0);

  unsigned kv[16];
  double bs = 0.0;
  #pragma unroll
  for (int c = 0; c < 16; ++c) { bs += (double)sims[c]; kv[c] = f2k(sims[c]); }
  if (!self_pos && ((i & 255) == tid)) kv[i >> 8] = 0xFFFFFFFFu;

  bs = wsum_d(bs);
  if (lane == 0) redD[w] = bs;
  __syncthreads();
  const float basef = (float)((redD[0] + redD[1] + redD[2] + redD[3]) * (1.0 / NN));

  // exact bitwise binary search (round-10 proven)
  unsigned lo = 0;
  int nLo = 0, nHi = NN, b = 31, par = 0;
  while (b >= 0 && (nHi - nLo) > 64) {
    unsigned mid = lo | (1u << b);
    int c = 0;
    #pragma unroll
    for (int t = 0; t < 16; ++t) c += (kv[t] < mid) ? 1 : 0;
    c = wsum_i(c);
    if (lane == 0) redI[par][w] = c;
    __syncthreads();
    c = redI[par][0] + redI[par][1] + redI[par][2] + redI[par][3];
    par ^= 1;
    if (c <= KSEL) { lo = mid; nLo = c; }
    else nHi = c;
    --b;
  }
  unsigned keysel;
  if ((nHi - nLo) <= 64) {
    const int shift = b + 1;
    const unsigned pfx = lo >> shift;
    if (tid == 0) ccount = 0;
    __syncthreads();
    #pragma unroll
    for (int t = 0; t < 16; ++t)
      if ((kv[t] >> shift) == pfx) { int p = atomicAdd(&ccount, 1); cbuf[p] = kv[t]; }
    __syncthreads();
    const int total = ccount;
    unsigned v = cbuf[lane];
    unsigned long long amask = (total >= 64) ? ~0ull : ((1ull << total) - 1ull);
    int ww = KSEL - nLo;
    for (int bb = b; bb >= 0; --bb) {
      unsigned long long z = __ballot(((amask >> lane) & 1ull) &&
                                      (((v >> bb) & 1u) == 0u));
      int zc = __popcll(z);
      if (ww < zc) amask = z;
      else { ww -= zc; amask &= ~z; }
    }
    int first = __ffsll((unsigned long long)amask) - 1;
    keysel = __shfl(v, first, 64);
  } else {
    keysel = lo;
  }
  const float thr = k2f(keysel);

  double psum = 0.0, nsum = 0.0;
  float minp = __builtin_inff();
  int hasp = 0;
  double pss = 0.0, nss = 0.0;
  int pct = 0, nct = 0;
  #pragma unroll
  for (int c = 0; c < 16; ++c) {
    const int j = (c << 8) + tid;
    const float s = k2f(kv[c]);   // NaN for excluded self
    const bool same = (tgt[j] == ti);
    const bool vpos = same && ((j == i) ? self_pos : (s < 1.0f));
    if (vpos) { minp = fminf(minp, s); pss += (double)s; pct++; }
    if (!same) { nss += (double)s; nct++; }
    if (s < thr) {
      float wgt = expf(ALPHA_C * (basef - s));
      if (vpos) { psum += (double)wgt; hasp = 1; }
      else if (!same) nsum += (double)wgt;
    }
  }
  psum = wsum_d(psum); nsum = wsum_d(nsum);
  minp = wmin_f(minp); hasp = wsum_i(hasp);
  if (lane == 0) { redP[w] = psum; redN[w] = nsum; redM[w] = minp; redH[w] = hasp; }
  __syncthreads();
  const double tpsum = redP[0] + redP[1] + redP[2] + redP[3];
  const double tnsum = redN[0] + redN[1] + redN[2] + redN[3];
  const float  tminp = fminf(fminf(redM[0], redM[1]), fminf(redM[2], redM[3]));
  const int    thasp = redH[0] + redH[1] + redH[2] + redH[3];

  if (i == NN - 1) {
    __syncthreads();
    pss = wsum_d(pss); nss = wsum_d(nss);
    pct = wsum_i(pct); nct = wsum_i(nct);
    if (lane == 0) { redP[w] = pss; redN[w] = nss; redC[w] = pct; redC2[w] = nct; }
    __syncthreads();
    if (tid == 0) {
      out[2] = (float)((redP[0] + redP[1] + redP[2] + redP[3]) /
                       (double)(redC[0] + redC[1] + redC[2] + redC[3]));
      out[3] = (float)((redN[0] + redN[1] + redN[2] + redN[3]) /
                       (double)(redC2[0] + redC2[1] + redC2[2] + redC2[3]));
    }
  }
  if (tid == 0) {
    float pl = (thasp > 0) ? (float)tpsum : expf(ALPHA_C * (basef - tminp));
    row_loss[i] = -logf(pl / (pl + (float)tnsum));
  }
}

// ---- kernel 5: deterministic mean of per-row losses ----
__global__ void nca_final(const float* __restrict__ row_loss, float* __restrict__ out) {
  __shared__ double redd[4];
  int tid = threadIdx.x;
  double s = 0.0;
  for (int i = tid; i < NN; i += 256) s += (double)row_loss[i];
  #pragma unroll
  for (int m = 32; m; m >>= 1) s += __shfl_xor(s, m, 64);
  if ((tid & 63) == 0) redd[tid >> 6] = s;
  __syncthreads();
  if (tid == 0) {
    double tot = redd[0] + redd[1] + redd[2] + redd[3];
    out[0] = (float)(tot * (1.0 / NN));
    out[1] = 0.0f;
  }
}

extern "C" void kernel_launch(void* const* d_in, const int* in_sizes, int n_in,
                              void* d_out, int out_size, void* d_ws, size_t ws_size,
                              hipStream_t stream) {
  const float* x  = (const float*)d_in[0];
  const int* tgt  = (const int*)d_in[1];
  float* out      = (float*)d_out;

  // ws: xhi 1MB | xlo 1MB | row_loss 16KB | part 2MB | winbuf 4MB | wincnt | flag
  short* xhi      = (short*)d_ws;
  short* xlo      = xhi + (size_t)NN * DD;
  float* row_loss = (float*)(xlo + (size_t)NN * DD);
  unsigned* part  = (unsigned*)(row_loss + NN);
  uint2* winbuf   = (uint2*)(part + (size_t)NN * 16 * 8);
  int* wincnt     = (int*)(winbuf + (size_t)NN * WCAP);
  int* flag       = wincnt + NN;

  nca_prep<<<(NN * DD / 8) / 256, 256, 0, stream>>>(x, xhi, xlo, wincnt, flag);
  nca_gemm<<<(NN / 32) * (NN / 256), 256, 0, stream>>>(xhi, xlo, tgt, part, winbuf, wincnt);
  nca_combine<<<NN / 4, 256, 0, stream>>>(x, part, winbuf, wincnt, flag, row_loss, out);
  nca_fallback<<<NN, 256, 0, stream>>>(x, tgt, flag, row_loss, out);
  nca_final<<<1, 256, 0, stream>>>(row_loss, out);
}

// Round 16
// 64.180 us; speedup vs baseline: 6.3646x; 1.2132x over previous
//
#include <hip/hip_runtime.h>
#include <math.h>

#define NN 4096
#define DD 128
#define ALPHA_C 16.0f
#define KSEL 32         // threshold = (K+1)-th smallest, 0-based index K
#define P1F -0.245f     // pivots bracketing rank-32 for N(0,1/128) sims
#define P2F -0.19f
#define SLOTS 16        // window slots per (row, colblock); Poisson(3.3) P(>16)~1e-7

typedef __attribute__((ext_vector_type(8))) short bf16x8;
typedef __attribute__((ext_vector_type(4))) float f32x4;

// ---- float <-> order-preserving u32 key ----
__device__ __forceinline__ unsigned f2k(float f) {
  unsigned b = __float_as_uint(f);
  return (b & 0x80000000u) ? ~b : (b | 0x80000000u);
}
__device__ __forceinline__ float k2f(unsigned k) {
  unsigned b = (k & 0x80000000u) ? (k & 0x7FFFFFFFu) : ~k;
  return __uint_as_float(b);
}

// ---- wave (64-lane) butterfly reductions ----
__device__ __forceinline__ double wsum_d(double v) {
  #pragma unroll
  for (int m = 32; m; m >>= 1) v += __shfl_xor(v, m, 64);
  return v;
}
__device__ __forceinline__ int wsum_i(int v) {
  #pragma unroll
  for (int m = 32; m; m >>= 1) v += __shfl_xor(v, m, 64);
  return v;
}
__device__ __forceinline__ float wsum_f(float v) {
  #pragma unroll
  for (int m = 32; m; m >>= 1) v += __shfl_xor(v, m, 64);
  return v;
}
__device__ __forceinline__ float wmin_f(float v) {
  #pragma unroll
  for (int m = 32; m; m >>= 1) v = fminf(v, __shfl_xor(v, m, 64));
  return v;
}

// ---- kernel 1: split x -> bf16 hi/lo fragment-major; init flag ----
__global__ __launch_bounds__(256) void nca_prep(
    const float* __restrict__ x, short* __restrict__ xhi, short* __restrict__ xlo,
    int* __restrict__ flag) {
  const int f  = blockIdx.x * blockDim.x + threadIdx.x;  // 0 .. N*D/8-1
  if (f == 0) flag[0] = 0;
  const int l  = f & 63;
  const int kb = (f >> 6) & 3;
  const int rg = f >> 8;
  const int row = (rg << 4) + (l & 15);
  const int k0  = (kb << 5) + ((l >> 4) << 3);
  const float* src = x + (size_t)row * DD + k0;
  float4 v0 = *reinterpret_cast<const float4*>(src);
  float4 v1 = *reinterpret_cast<const float4*>(src + 4);
  float vv[8] = {v0.x, v0.y, v0.z, v0.w, v1.x, v1.y, v1.z, v1.w};
  bf16x8 h, lo;
  #pragma unroll
  for (int q = 0; q < 8; ++q) {
    unsigned u  = __float_as_uint(vv[q]);
    unsigned hb = (u + 0x7FFFu + ((u >> 16) & 1u)) >> 16;
    float hf    = __uint_as_float(hb << 16);
    float lf    = vv[q] - hf;
    unsigned ul = __float_as_uint(lf);
    unsigned lb = (ul + 0x7FFFu + ((ul >> 16) & 1u)) >> 16;
    h[q] = (short)hb; lo[q] = (short)lb;
  }
  *reinterpret_cast<bf16x8*>(xhi + (size_t)f * 8) = h;
  *reinterpret_cast<bf16x8*>(xlo + (size_t)f * 8) = lo;
}

// ---- kernel 2: fused MFMA GEMM + selection epilogue (LDS-local appends) ----
// part record per (row, cg), 8 u32: 0 base f32 | 1 pes f32 | 2 nes f32 |
// 3 minp f32 | 4 c1|pc1<<12|wc<<24 | 5 pos_s | 6 neg_s | 7 pos_c|neg_c<<16.
// Window entries go to FIXED slots winbuf[row][cg*16+slot], slot from a
// per-block LDS counter (no global atomics, no ballots in the hot loop).
__global__ __launch_bounds__(256) void nca_gemm(
    const short* __restrict__ xhi, const short* __restrict__ xlo,
    const int* __restrict__ tgt, unsigned* __restrict__ part,
    uint2* __restrict__ winbuf) {
  __shared__ unsigned state[4][32][8];   // 4 KB: per-wave per-row partials
  __shared__ int wcl[32];                // per-(row,cg) window counters

  const int tid = threadIdx.x;
  const int w   = tid >> 6;
  const int l   = tid & 63;
  const int rg  = blockIdx.x >> 4;
  const int cg  = blockIdx.x & 15;
  const int R   = rg << 5;                 // 32 rows
  const int C   = (cg << 8) + (w << 6);    // 64 cols per wave
  const int rga = rg << 1;
  const int rgb = (cg << 4) + (w << 2);

  if (tid < 32) wcl[tid] = 0;
  __syncthreads();

  f32x4 acc[2][4];
  #pragma unroll
  for (int rt = 0; rt < 2; ++rt)
    #pragma unroll
    for (int t = 0; t < 4; ++t) acc[rt][t] = (f32x4){0.f, 0.f, 0.f, 0.f};

  #pragma unroll
  for (int kb = 0; kb < 4; ++kb) {
    bf16x8 ah[2], al[2], bh[4], bl[4];
    #pragma unroll
    for (int rt = 0; rt < 2; ++rt) {
      const size_t off = ((size_t)((rga + rt) * 4 + kb) * 64 + l) * 8;
      ah[rt] = *reinterpret_cast<const bf16x8*>(xhi + off);
      al[rt] = *reinterpret_cast<const bf16x8*>(xlo + off);
    }
    #pragma unroll
    for (int t = 0; t < 4; ++t) {
      const size_t off = ((size_t)((rgb + t) * 4 + kb) * 64 + l) * 8;
      bh[t] = *reinterpret_cast<const bf16x8*>(xhi + off);
      bl[t] = *reinterpret_cast<const bf16x8*>(xlo + off);
    }
    #pragma unroll
    for (int rt = 0; rt < 2; ++rt)
      #pragma unroll
      for (int t = 0; t < 4; ++t) {
        acc[rt][t] = __builtin_amdgcn_mfma_f32_16x16x32_bf16(ah[rt], bh[t], acc[rt][t], 0, 0, 0);
        acc[rt][t] = __builtin_amdgcn_mfma_f32_16x16x32_bf16(ah[rt], bl[t], acc[rt][t], 0, 0, 0);
        acc[rt][t] = __builtin_amdgcn_mfma_f32_16x16x32_bf16(al[rt], bh[t], acc[rt][t], 0, 0, 0);
      }
  }

  // ---- selection epilogue ----
  // C/D layout (m89-verified): col = lane&15, row = (lane>>4)*4 + reg
  const int rbase = (l >> 4) << 2;
  const int cc    = l & 15;
  const unsigned P1k = f2k(P1F), P2k = f2k(P2F);
  const bool diagblk = (R + 32 == NN);     // block containing row NN-1

  int tr[2][4], tc[4];
  #pragma unroll
  for (int rt = 0; rt < 2; ++rt)
    #pragma unroll
    for (int r = 0; r < 4; ++r) tr[rt][r] = tgt[R + (rt << 4) + rbase + r];
  #pragma unroll
  for (int t = 0; t < 4; ++t) tc[t] = tgt[C + (t << 4) + cc];

  #pragma unroll
  for (int rt = 0; rt < 2; ++rt) {
    #pragma unroll
    for (int r = 0; r < 4; ++r) {
      const int row_l = (rt << 4) + rbase + r;
      const int grow  = R + row_l;
      float base4 = 0.f, pes4 = 0.f, nes4 = 0.f, minp4 = __builtin_inff();
      float pos4 = 0.f, neg4 = 0.f;
      int cnts4 = 0;   // bytes: c1 | pc1<<8 | pos_c<<16 | neg_c<<24 (each <=4/lane)
      #pragma unroll
      for (int t = 0; t < 4; ++t) {
        const float s = acc[rt][t][r];
        const int j = C + (t << 4) + cc;
        const bool same  = (tc[t] == tr[rt][r]);
        const bool nself = (j != grow);
        const unsigned key = f2k(s);
        base4 += s;                            // base includes self
        const float e = __expf(-ALPHA_C * s);  // always: v_exp path, no branch
        const bool below = nself && (key < P1k);
        pes4 += (below && same)  ? e : 0.f;
        nes4 += (below && !same) ? e : 0.f;
        cnts4 += below ? 1 : 0;
        cnts4 += (below && same) ? (1 << 8) : 0;
        const bool vp = nself && same && (s < 1.0f);
        minp4 = vp ? fminf(minp4, s) : minp4;
        if (diagblk) {                         // block-uniform branch
          pos4 += vp ? s : 0.f;
          cnts4 += vp ? (1 << 16) : 0;
          neg4 += (!same) ? s : 0.f;
          cnts4 += (!same) ? (1 << 24) : 0;
        }
        const bool inwin = nself && (key >= P1k) && (key < P2k);
        if (inwin) {                           // LDS atomic: ~40cyc, no ballot
          int slot = atomicAdd(&wcl[row_l], 1);
          if (slot < SLOTS)
            winbuf[(size_t)grow * 256 + (cg << 4) + slot] =
                make_uint2(key, same ? 1u : 0u);
        }
      }
      // combine the 16 lanes sharing this row (xor masks stay in-quarter)
      #pragma unroll
      for (int m = 1; m < 16; m <<= 1) {
        base4 += __shfl_xor(base4, m, 64);
        pes4  += __shfl_xor(pes4,  m, 64);
        nes4  += __shfl_xor(nes4,  m, 64);
        minp4  = fminf(minp4, __shfl_xor(minp4, m, 64));
        cnts4 += __shfl_xor(cnts4, m, 64);
        if (diagblk) {
          pos4 += __shfl_xor(pos4, m, 64);
          neg4 += __shfl_xor(neg4, m, 64);
        }
      }
      if ((l & 15) == 0) {
        unsigned* st = &state[w][row_l][0];
        st[0] = __float_as_uint(base4); st[1] = __float_as_uint(pes4);
        st[2] = __float_as_uint(nes4);  st[3] = __float_as_uint(minp4);
        st[4] = (unsigned)cnts4;        st[5] = __float_as_uint(pos4);
        st[6] = __float_as_uint(neg4);  st[7] = (unsigned)cnts4;
      }
    }
  }
  __syncthreads();

  // cross-wave combine: thread -> (row, field); widen packed counts
  {
    const int row = tid >> 3, fld = tid & 7;
    unsigned v0 = state[0][row][fld], v1 = state[1][row][fld];
    unsigned v2 = state[2][row][fld], v3 = state[3][row][fld];
    unsigned res;
    if (fld == 4) {
      unsigned a = (v0 & 255) + (v1 & 255) + (v2 & 255) + (v3 & 255);
      unsigned b = ((v0 >> 8) & 255) + ((v1 >> 8) & 255) + ((v2 >> 8) & 255) + ((v3 >> 8) & 255);
      unsigned wcv = (unsigned)wcl[row]; if (wcv > 255) wcv = 255;
      res = a | (b << 12) | (wcv << 24);
    } else if (fld == 7) {
      unsigned a = ((v0 >> 16) & 255) + ((v1 >> 16) & 255) + ((v2 >> 16) & 255) + ((v3 >> 16) & 255);
      unsigned b = (v0 >> 24) + (v1 >> 24) + (v2 >> 24) + (v3 >> 24);
      res = a | (b << 16);
    } else if (fld == 3) {
      res = __float_as_uint(fminf(fminf(__uint_as_float(v0), __uint_as_float(v1)),
                                  fminf(__uint_as_float(v2), __uint_as_float(v3))));
    } else {
      res = __float_as_uint(__uint_as_float(v0) + __uint_as_float(v1) +
                            __uint_as_float(v2) + __uint_as_float(v3));
    }
    part[((size_t)(R + row) * 16 + fld == 4 ? ((size_t)(R + row) * 16 + cg) * 8 + 4
                                            : ((size_t)(R + row) * 16 + cg) * 8 + fld)] = res;
  }
}

// ---- kernel 3: per-row combine. 1 wave = 1 row; atomic-free. ----
__global__ __launch_bounds__(256) void nca_combine(
    const float* __restrict__ x, const unsigned* __restrict__ part,
    const uint2* __restrict__ winbuf, int* __restrict__ flag,
    float* __restrict__ row_loss, float* __restrict__ out) {
  const int tid = threadIdx.x, w = tid >> 6, lane = tid & 63;
  const int i = blockIdx.x * 4 + w;

  // f64 self-dot (decision sim[i][i] < 1.0)
  double sx0 = (double)x[(size_t)i * DD + lane];
  double sx1 = (double)x[(size_t)i * DD + lane + 64];
  const double selfd = wsum_d(sx0 * sx0 + sx1 * sx1);
  const bool self_pos = (selfd < 1.0);

  // gather 16 partials
  float base = 0.f, pes = 0.f, nes = 0.f, minp = __builtin_inff();
  float pos_s = 0.f, neg_s = 0.f;
  int c1 = 0, pc1 = 0, pos_c = 0, neg_c = 0, wc = 0;
  if (lane < 16) {
    const unsigned* p = &part[((size_t)i * 16 + lane) * 8];
    uint4 a = *reinterpret_cast<const uint4*>(p);
    uint4 b = *reinterpret_cast<const uint4*>(p + 4);
    base = __uint_as_float(a.x); pes = __uint_as_float(a.y);
    nes  = __uint_as_float(a.z); minp = __uint_as_float(a.w);
    c1 = b.x & 0xFFF; pc1 = (b.x >> 12) & 0xFFF; wc = (int)(b.x >> 24);
    pos_s = __uint_as_float(b.y); neg_s = __uint_as_float(b.z);
    pos_c = b.w & 0xFFFF; neg_c = b.w >> 16;
  }
  base = wsum_f(base); pes = wsum_f(pes); nes = wsum_f(nes);
  minp = wmin_f(minp);
  const int ovf = (int)(__ballot(wc > SLOTS) != 0ull);
  const int wt  = wsum_i(wc);
  c1 = wsum_i(c1); pc1 = wsum_i(pc1);
  pos_s = wsum_f(pos_s); neg_s = wsum_f(neg_s);
  pos_c = wsum_i(pos_c); neg_c = wsum_i(neg_c);

  const bool fast = (c1 <= KSEL) && (c1 + wt > KSEL) && (!ovf);
  if (!fast) {           // exact fallback will recompute this row
    if (lane == 0) { int p = atomicAdd(&flag[0], 1); flag[1 + p] = i; }
    return;
  }

  // gather 4 fixed-slot entries per lane; validity from per-cg wc
  unsigned k[4] = {0xFFFFFFFFu, 0xFFFFFFFFu, 0xFFFFFFFFu, 0xFFFFFFFFu};
  unsigned sm[4] = {0u, 0u, 0u, 0u};
  const int wcl16 = (lane < 16) ? wc : 0;   // wc valid on lanes 0..15
  #pragma unroll
  for (int q = 0; q < 4; ++q) {
    const int cgq = (lane >> 4) + (q << 2);
    const int wcq = __shfl(wcl16, cgq, 64);
    if ((lane & 15) < wcq) {
      uint2 e = winbuf[(size_t)i * 256 + (q << 6) + lane];
      k[q] = e.x; sm[q] = e.y;
    }
  }

  // rank-r window key: max u with count(keys < u) <= r (round-2-verified)
  const int r = KSEL - c1;               // 0 <= r < wt by guard
  unsigned thrkey = 0;
  for (int b = 31; b >= 0; --b) {
    unsigned mid = thrkey | (1u << b);
    int c = 0;
    #pragma unroll
    for (int q = 0; q < 4; ++q)
      c += (int)__popcll(__ballot(k[q] < mid));
    if (c <= r) thrkey = mid;
  }

  float wp = 0.f, wn = 0.f; int hp = 0;
  #pragma unroll
  for (int q = 0; q < 4; ++q) {
    if (k[q] < thrkey) {
      float e = expf(-ALPHA_C * k2f(k[q]));
      if (sm[q]) { wp += e; hp = 1; } else wn += e;
    }
  }
  wp = wsum_f(wp); wn = wsum_f(wn); hp = wsum_i(hp);

  const float basem = base * (1.0f / NN);
  const float eb = expf(ALPHA_C * basem);      // exp(a(base-s)) = eb*exp(-a*s)
  const float minp2 = self_pos ? fminf(minp, (float)selfd) : minp;
  const bool haspos = (pc1 > 0) || (hp > 0);
  const float pl = haspos ? eb * (pes + wp) : expf(ALPHA_C * (basem - minp2));
  const float nl = eb * (nes + wn);
  if (lane == 0) row_loss[i] = -logf(pl / (pl + nl));

  if (i == NN - 1 && lane == 0) {              // diagnostics from last row
    float ps = pos_s + (self_pos ? (float)selfd : 0.f);
    int   pc = pos_c + (self_pos ? 1 : 0);
    out[2] = ps / (float)pc;
    out[3] = neg_s / (float)neg_c;
  }
}

// ---- kernel 4: exact fallback, 1 block per flagged row (early exit) ----
__global__ __launch_bounds__(256) void nca_fallback(
    const float* __restrict__ x, const int* __restrict__ tgt,
    const int* __restrict__ flag, float* __restrict__ row_loss,
    float* __restrict__ out) {
  __shared__ float xi[DD];
  __shared__ double redD[4];
  __shared__ int redI[2][4];
  __shared__ double redP[4], redN[4];
  __shared__ float redM[4];
  __shared__ int redH[4], redC[4], redC2[4];
  __shared__ unsigned cbuf[64];
  __shared__ int ccount;

  const int nf = flag[0];
  if (blockIdx.x >= nf) return;
  const int tid = threadIdx.x, w = tid >> 6, lane = tid & 63;
  const int i = flag[1 + blockIdx.x];
  const int ti = tgt[i];
  if (tid < DD) xi[tid] = x[(size_t)i * DD + tid];
  __syncthreads();

  // sims: thread owns cols j = c*256 + tid
  float sims[16];
  const float4* xiv = reinterpret_cast<const float4*>(xi);
  for (int c = 0; c < 16; ++c) {
    const int j = (c << 8) + tid;
    const float4* xj = reinterpret_cast<const float4*>(x + (size_t)j * DD);
    float a0 = 0, a1 = 0, a2 = 0, a3 = 0;
    #pragma unroll
    for (int d = 0; d < 32; ++d) {
      float4 u = xiv[d]; float4 v = xj[d];
      a0 = fmaf(u.x, v.x, a0); a1 = fmaf(u.y, v.y, a1);
      a2 = fmaf(u.z, v.z, a2); a3 = fmaf(u.w, v.w, a3);
    }
    sims[c] = (a0 + a1) + (a2 + a3);
  }

  double sx0 = (double)xi[lane], sx1 = (double)xi[lane + 64];
  const double selfd = wsum_d(sx0 * sx0 + sx1 * sx1);
  const bool self_pos = (selfd < 1.0);

  unsigned kv[16];
  double bs = 0.0;
  #pragma unroll
  for (int c = 0; c < 16; ++c) { bs += (double)sims[c]; kv[c] = f2k(sims[c]); }
  if (!self_pos && ((i & 255) == tid)) kv[i >> 8] = 0xFFFFFFFFu;

  bs = wsum_d(bs);
  if (lane == 0) redD[w] = bs;
  __syncthreads();
  const float basef = (float)((redD[0] + redD[1] + redD[2] + redD[3]) * (1.0 / NN));

  // exact bitwise binary search (round-10 proven)
  unsigned lo = 0;
  int nLo = 0, nHi = NN, b = 31, par = 0;
  while (b >= 0 && (nHi - nLo) > 64) {
    unsigned mid = lo | (1u << b);
    int c = 0;
    #pragma unroll
    for (int t = 0; t < 16; ++t) c += (kv[t] < mid) ? 1 : 0;
    c = wsum_i(c);
    if (lane == 0) redI[par][w] = c;
    __syncthreads();
    c = redI[par][0] + redI[par][1] + redI[par][2] + redI[par][3];
    par ^= 1;
    if (c <= KSEL) { lo = mid; nLo = c; }
    else nHi = c;
    --b;
  }
  unsigned keysel;
  if ((nHi - nLo) <= 64) {
    const int shift = b + 1;
    const unsigned pfx = lo >> shift;
    if (tid == 0) ccount = 0;
    __syncthreads();
    #pragma unroll
    for (int t = 0; t < 16; ++t)
      if ((kv[t] >> shift) == pfx) { int p = atomicAdd(&ccount, 1); cbuf[p] = kv[t]; }
    __syncthreads();
    const int total = ccount;
    unsigned v = cbuf[lane];
    unsigned long long amask = (total >= 64) ? ~0ull : ((1ull << total) - 1ull);
    int ww = KSEL - nLo;
    for (int bb = b; bb >= 0; --bb) {
      unsigned long long z = __ballot(((amask >> lane) & 1ull) &&
                                      (((v >> bb) & 1u) == 0u));
      int zc = __popcll(z);
      if (ww < zc) amask = z;
      else { ww -= zc; amask &= ~z; }
    }
    int first = __ffsll((unsigned long long)amask) - 1;
    keysel = __shfl(v, first, 64);
  } else {
    keysel = lo;
  }
  const float thr = k2f(keysel);

  double psum = 0.0, nsum = 0.0;
  float minp = __builtin_inff();
  int hasp = 0;
  double pss = 0.0, nss = 0.0;
  int pct = 0, nct = 0;
  #pragma unroll
  for (int c = 0; c < 16; ++c) {
    const int j = (c << 8) + tid;
    const float s = k2f(kv[c]);   // NaN for excluded self
    const bool same = (tgt[j] == ti);
    const bool vpos = same && ((j == i) ? self_pos : (s < 1.0f));
    if (vpos) { minp = fminf(minp, s); pss += (double)s; pct++; }
    if (!same) { nss += (double)s; nct++; }
    if (s < thr) {
      float wgt = expf(ALPHA_C * (basef - s));
      if (vpos) { psum += (double)wgt; hasp = 1; }
      else if (!same) nsum += (double)wgt;
    }
  }
  psum = wsum_d(psum); nsum = wsum_d(nsum);
  minp = wmin_f(minp); hasp = wsum_i(hasp);
  if (lane == 0) { redP[w] = psum; redN[w] = nsum; redM[w] = minp; redH[w] = hasp; }
  __syncthreads();
  const double tpsum = redP[0] + redP[1] + redP[2] + redP[3];
  const double tnsum = redN[0] + redN[1] + redN[2] + redN[3];
  const float  tminp = fminf(fminf(redM[0], redM[1]), fminf(redM[2], redM[3]));
  const int    thasp = redH[0] + redH[1] + redH[2] + redH[3];

  if (i == NN - 1) {
    __syncthreads();
    pss = wsum_d(pss); nss = wsum_d(nss);
    pct = wsum_i(pct); nct = wsum_i(nct);
    if (lane == 0) { redP[w] = pss; redN[w] = nss; redC[w] = pct; redC2[w] = nct; }
    __syncthreads();
    if (tid == 0) {
      out[2] = (float)((redP[0] + redP[1] + redP[2] + redP[3]) /
                       (double)(redC[0] + redC[1] + redC[2] + redC[3]));
      out[3] = (float)((redN[0] + redN[1] + redN[2] + redN[3]) /
                       (double)(redC2[0] + redC2[1] + redC2[2] + redC2[3]));
    }
  }
  if (tid == 0) {
    float pl = (thasp > 0) ? (float)tpsum : expf(ALPHA_C * (basef - tminp));
    row_loss[i] = -logf(pl / (pl + (float)tnsum));
  }
}

// ---- kernel 5: deterministic mean of per-row losses ----
__global__ void nca_final(const float* __restrict__ row_loss, float* __restrict__ out) {
  __shared__ double redd[4];
  int tid = threadIdx.x;
  double s = 0.0;
  for (int i = tid; i < NN; i += 256) s += (double)row_loss[i];
  #pragma unroll
  for (int m = 32; m; m >>= 1) s += __shfl_xor(s, m, 64);
  if ((tid & 63) == 0) redd[tid >> 6] = s;
  __syncthreads();
  if (tid == 0) {
    double tot = redd[0] + redd[1] + redd[2] + redd[3];
    out[0] = (float)(tot * (1.0 / NN));
    out[1] = 0.0f;
  }
}

extern "C" void kernel_launch(void* const* d_in, const int* in_sizes, int n_in,
                              void* d_out, int out_size, void* d_ws, size_t ws_size,
                              hipStream_t stream) {
  const float* x  = (const float*)d_in[0];
  const int* tgt  = (const int*)d_in[1];
  float* out      = (float*)d_out;

  // ws: xhi 1MB | xlo 1MB | row_loss 16KB | part 2MB | winbuf 8MB | flag
  short* xhi      = (short*)d_ws;
  short* xlo      = xhi + (size_t)NN * DD;
  float* row_loss = (float*)(xlo + (size_t)NN * DD);
  unsigned* part  = (unsigned*)(row_loss + NN);
  uint2* winbuf   = (uint2*)(part + (size_t)NN * 16 * 8);
  int* flag       = (int*)(winbuf + (size_t)NN * 256);

  nca_prep<<<(NN * DD / 8) / 256, 256, 0, stream>>>(x, xhi, xlo, flag);
  nca_gemm<<<(NN / 32) * (NN / 256), 256, 0, stream>>>(xhi, xlo, tgt, part, winbuf);
  nca_combine<<<NN / 4, 256, 0, stream>>>(x, part, winbuf, flag, row_loss, out);
  nca_fallback<<<NN, 256, 0, stream>>>(x, tgt, flag, row_loss, out);
  nca_final<<<1, 256, 0, stream>>>(row_loss, out);
}

// Round 17
// 49.421 us; speedup vs baseline: 8.2652x; 1.2986x over previous
//
#include <hip/hip_runtime.h>
#include <math.h>

#define NN 4096
#define DD 128
#define ALPHA_C 16.0f
#define KSEL 32         // threshold = (K+1)-th smallest, 0-based index K
#define P2F -0.19f      // pivot: rank-32 of N(0,1/128) sims is ~-0.213, below P2
#define SLOTS 16        // slots per (row, colblock); appends ~Poisson(4.6)

typedef __attribute__((ext_vector_type(8))) short bf16x8;
typedef __attribute__((ext_vector_type(4))) float f32x4;

// ---- float <-> order-preserving u32 key ----
__device__ __forceinline__ unsigned f2k(float f) {
  unsigned b = __float_as_uint(f);
  return (b & 0x80000000u) ? ~b : (b | 0x80000000u);
}
__device__ __forceinline__ float k2f(unsigned k) {
  unsigned b = (k & 0x80000000u) ? (k & 0x7FFFFFFFu) : ~k;
  return __uint_as_float(b);
}

// ---- wave (64-lane) butterfly reductions ----
__device__ __forceinline__ double wsum_d(double v) {
  #pragma unroll
  for (int m = 32; m; m >>= 1) v += __shfl_xor(v, m, 64);
  return v;
}
__device__ __forceinline__ int wsum_i(int v) {
  #pragma unroll
  for (int m = 32; m; m >>= 1) v += __shfl_xor(v, m, 64);
  return v;
}
__device__ __forceinline__ float wsum_f(float v) {
  #pragma unroll
  for (int m = 32; m; m >>= 1) v += __shfl_xor(v, m, 64);
  return v;
}
__device__ __forceinline__ float wmin_f(float v) {
  #pragma unroll
  for (int m = 32; m; m >>= 1) v = fminf(v, __shfl_xor(v, m, 64));
  return v;
}

// ---- kernel 1: split x -> bf16 hi/lo fragment-major; init flag ----
__global__ __launch_bounds__(256) void nca_prep(
    const float* __restrict__ x, short* __restrict__ xhi, short* __restrict__ xlo,
    int* __restrict__ flag) {
  const int f  = blockIdx.x * blockDim.x + threadIdx.x;  // 0 .. N*D/8-1
  if (f == 0) flag[0] = 0;
  const int l  = f & 63;
  const int kb = (f >> 6) & 3;
  const int rg = f >> 8;
  const int row = (rg << 4) + (l & 15);
  const int k0  = (kb << 5) + ((l >> 4) << 3);
  const float* src = x + (size_t)row * DD + k0;
  float4 v0 = *reinterpret_cast<const float4*>(src);
  float4 v1 = *reinterpret_cast<const float4*>(src + 4);
  float vv[8] = {v0.x, v0.y, v0.z, v0.w, v1.x, v1.y, v1.z, v1.w};
  bf16x8 h, lo;
  #pragma unroll
  for (int q = 0; q < 8; ++q) {
    unsigned u  = __float_as_uint(vv[q]);
    unsigned hb = (u + 0x7FFFu + ((u >> 16) & 1u)) >> 16;
    float hf    = __uint_as_float(hb << 16);
    float lf    = vv[q] - hf;
    unsigned ul = __float_as_uint(lf);
    unsigned lb = (ul + 0x7FFFu + ((ul >> 16) & 1u)) >> 16;
    h[q] = (short)hb; lo[q] = (short)lb;
  }
  *reinterpret_cast<bf16x8*>(xhi + (size_t)f * 8) = h;
  *reinterpret_cast<bf16x8*>(xlo + (size_t)f * 8) = lo;
}

// ---- kernel 2: fused MFMA GEMM + MINIMAL epilogue ----
// Exports only: (a) candidate list per row = all values with key<P2 plus ALL
// non-self same-class values (tagged), into fixed slots winbuf[row][cg*16+s];
// (b) true per-(row,cg) counts wcbuf; (c) last-row neg sum (16 diag blocks).
// base is DROPPED: loss = -log(pl/(pl+nl)) is exactly invariant to the
// exp(alpha*base) common factor. No exp, no field reduces, no part array.
__global__ __launch_bounds__(256) void nca_gemm(
    const short* __restrict__ xhi, const short* __restrict__ xlo,
    const int* __restrict__ tgt, uint2* __restrict__ winbuf,
    unsigned char* __restrict__ wcbuf, float* __restrict__ diagneg) {
  __shared__ int wcl[32];                // per-(row,cg) append counters

  const int tid = threadIdx.x;
  const int w   = tid >> 6;
  const int l   = tid & 63;
  const int rg  = blockIdx.x >> 4;
  const int cg  = blockIdx.x & 15;
  const int R   = rg << 5;                 // 32 rows
  const int C   = (cg << 8) + (w << 6);    // 64 cols per wave
  const int rga = rg << 1;
  const int rgb = (cg << 4) + (w << 2);

  if (tid < 32) wcl[tid] = 0;
  __syncthreads();

  f32x4 acc[2][4];
  #pragma unroll
  for (int rt = 0; rt < 2; ++rt)
    #pragma unroll
    for (int t = 0; t < 4; ++t) acc[rt][t] = (f32x4){0.f, 0.f, 0.f, 0.f};

  #pragma unroll
  for (int kb = 0; kb < 4; ++kb) {
    bf16x8 ah[2], al[2], bh[4], bl[4];
    #pragma unroll
    for (int rt = 0; rt < 2; ++rt) {
      const size_t off = ((size_t)((rga + rt) * 4 + kb) * 64 + l) * 8;
      ah[rt] = *reinterpret_cast<const bf16x8*>(xhi + off);
      al[rt] = *reinterpret_cast<const bf16x8*>(xlo + off);
    }
    #pragma unroll
    for (int t = 0; t < 4; ++t) {
      const size_t off = ((size_t)((rgb + t) * 4 + kb) * 64 + l) * 8;
      bh[t] = *reinterpret_cast<const bf16x8*>(xhi + off);
      bl[t] = *reinterpret_cast<const bf16x8*>(xlo + off);
    }
    #pragma unroll
    for (int rt = 0; rt < 2; ++rt)
      #pragma unroll
      for (int t = 0; t < 4; ++t) {
        acc[rt][t] = __builtin_amdgcn_mfma_f32_16x16x32_bf16(ah[rt], bh[t], acc[rt][t], 0, 0, 0);
        acc[rt][t] = __builtin_amdgcn_mfma_f32_16x16x32_bf16(ah[rt], bl[t], acc[rt][t], 0, 0, 0);
        acc[rt][t] = __builtin_amdgcn_mfma_f32_16x16x32_bf16(al[rt], bh[t], acc[rt][t], 0, 0, 0);
      }
  }

  // ---- minimal epilogue ----
  // C/D layout (m89-verified): col = lane&15, row = (lane>>4)*4 + reg
  const int rbase = (l >> 4) << 2;
  const int cc    = l & 15;
  const unsigned P2k = f2k(P2F);
  const bool diagblk = (R + 32 == NN);

  int tr[2][4], tc[4];
  #pragma unroll
  for (int rt = 0; rt < 2; ++rt)
    #pragma unroll
    for (int r = 0; r < 4; ++r) tr[rt][r] = tgt[R + (rt << 4) + rbase + r];
  #pragma unroll
  for (int t = 0; t < 4; ++t) tc[t] = tgt[C + (t << 4) + cc];

  #pragma unroll
  for (int rt = 0; rt < 2; ++rt) {
    #pragma unroll
    for (int r = 0; r < 4; ++r) {
      const int row_l = (rt << 4) + rbase + r;
      const int grow  = R + row_l;
      #pragma unroll
      for (int t = 0; t < 4; ++t) {
        const float s = acc[rt][t][r];
        const int j = C + (t << 4) + cc;
        const bool same = (tc[t] == tr[rt][r]);
        const unsigned key = f2k(s);
        const bool app = (j != grow) && (same || (key < P2k));
        if (app) {
          int slot = atomicAdd(&wcl[row_l], 1);
          if (slot < SLOTS)
            winbuf[(size_t)grow * 256 + (cg << 4) + slot] =
                make_uint2(key, same ? 1u : 0u);
        }
      }
    }
  }

  if (diagblk) {   // last-row (NN-1) negative-pair sim sum, 16 blocks only
    const int tN1 = tgt[NN - 1];
    float negs = 0.f;
    #pragma unroll
    for (int t = 0; t < 4; ++t)
      negs += (tc[t] != tN1) ? acc[1][t][3] : 0.f;
    negs = ((l >> 4) == 3) ? negs : 0.f;   // only group 3 holds row NN-1
    #pragma unroll
    for (int m = 1; m < 16; m <<= 1) negs += __shfl_xor(negs, m, 64);
    if (l == 48) diagneg[(cg << 2) + w] = negs;
  }

  __syncthreads();
  if (tid < 32) {
    int c = wcl[tid];
    wcbuf[(size_t)(R + tid) * 16 + cg] = (unsigned char)(c > 255 ? 255 : c);
  }
}

// ---- kernel 3: per-row combine. 1 wave = 1 row; complete info from list. ----
__global__ __launch_bounds__(256) void nca_combine(
    const float* __restrict__ x, const int* __restrict__ tgt,
    const uint2* __restrict__ winbuf, const unsigned char* __restrict__ wcbuf,
    const float* __restrict__ diagneg, int* __restrict__ flag,
    float* __restrict__ row_loss, float* __restrict__ out) {
  const int tid = threadIdx.x, w = tid >> 6, lane = tid & 63;
  const int i = blockIdx.x * 4 + w;

  // f64 self-dot (decision sim[i][i] < 1.0)
  double sx0 = (double)x[(size_t)i * DD + lane];
  double sx1 = (double)x[(size_t)i * DD + lane + 64];
  const double selfd = wsum_d(sx0 * sx0 + sx1 * sx1);
  const bool self_pos = (selfd < 1.0);

  // per-cg true counts; overflow -> exact fallback
  const int wcq_l = (lane < 16) ? (int)wcbuf[(size_t)i * 16 + lane] : 0;
  const bool ovf = (__ballot(wcq_l > SLOTS) != 0ull);

  // gather 4 fixed slots/lane: sigma = q*64+lane; cg = sigma>>4, slot = sigma&15
  unsigned k[4]  = {0xFFFFFFFFu, 0xFFFFFFFFu, 0xFFFFFFFFu, 0xFFFFFFFFu};
  unsigned sm[4] = {0u, 0u, 0u, 0u};
  #pragma unroll
  for (int q = 0; q < 4; ++q) {
    const int sigma = (q << 6) + lane;
    const int wcq = __shfl(wcq_l, sigma >> 4, 64);
    if ((sigma & 15) < (wcq < SLOTS ? wcq : SLOTS)) {
      uint2 e = winbuf[(size_t)i * 256 + sigma];
      k[q] = e.x; sm[q] = e.y;
    }
  }

  const unsigned P2k = f2k(P2F);
  int c2 = 0;
  #pragma unroll
  for (int q = 0; q < 4; ++q) c2 += (int)__popcll(__ballot(k[q] < P2k));
  const bool fast = (c2 > KSEL) && (!ovf);
  if (!fast) {
    if (lane == 0) { int p = atomicAdd(&flag[0], 1); flag[1 + p] = i; }
    return;
  }

  // exact rank-KSEL key: max u with count(keys < u) <= KSEL. Guard ensures
  // thrkey < P2k, where the list contains ALL row keys -> exact row rank.
  unsigned thrkey = 0;
  for (int b = 31; b >= 0; --b) {
    unsigned mid = thrkey | (1u << b);
    int c = 0;
    #pragma unroll
    for (int q = 0; q < 4; ++q) c += (int)__popcll(__ballot(k[q] < mid));
    if (c <= KSEL) thrkey = mid;
  }

  // weighted sums (base dropped: ratio-invariant), minpos, haspos
  float wp = 0.f, wn = 0.f, minp = __builtin_inff();
  int hp = 0;
  #pragma unroll
  for (int q = 0; q < 4; ++q) {
    const float s = k2f(k[q]);           // NaN for empty slots (sm=0, k=max)
    if (k[q] < thrkey) {
      float e = expf(-ALPHA_C * s);
      if (sm[q]) { wp += e; hp = 1; } else wn += e;
    }
    if (sm[q] && s < 1.0f) minp = fminf(minp, s);
  }
  wp = wsum_f(wp); wn = wsum_f(wn); hp = wsum_i(hp); minp = wmin_f(minp);

  const float minp2 = self_pos ? fminf(minp, (float)selfd) : minp;
  const float pl = hp ? wp : expf(-ALPHA_C * minp2);
  const float nl = wn;
  if (lane == 0) row_loss[i] = -logf(pl / (pl + nl));

  if (i == NN - 1) {                     // diagnostics from the last row
    float ps = 0.f; int pc = 0;
    #pragma unroll
    for (int q = 0; q < 4; ++q) {
      const float s = k2f(k[q]);
      if (sm[q] && s < 1.0f) { ps += s; pc++; }
    }
    ps = wsum_f(ps); pc = wsum_i(pc);
    float ns = wsum_f(diagneg[lane]);    // 64 partials from 16 diag blocks
    const int ti = tgt[NN - 1];
    int nc = 0;
    #pragma unroll
    for (int kk = 0; kk < 16; ++kk) {
      int4 t4 = *reinterpret_cast<const int4*>(tgt + (kk << 8) + (lane << 2));
      nc += (t4.x != ti) + (t4.y != ti) + (t4.z != ti) + (t4.w != ti);
    }
    nc = wsum_i(nc);
    if (lane == 0) {
      out[2] = (ps + (self_pos ? (float)selfd : 0.f)) /
               (float)(pc + (self_pos ? 1 : 0));
      out[3] = ns / (float)nc;
    }
  }
}

// ---- kernel 4: exact fallback, 1 block per flagged row (early exit) ----
__global__ __launch_bounds__(256) void nca_fallback(
    const float* __restrict__ x, const int* __restrict__ tgt,
    const int* __restrict__ flag, float* __restrict__ row_loss,
    float* __restrict__ out) {
  __shared__ float xi[DD];
  __shared__ double redD[4];
  __shared__ int redI[2][4];
  __shared__ double redP[4], redN[4];
  __shared__ float redM[4];
  __shared__ int redH[4], redC[4], redC2[4];
  __shared__ unsigned cbuf[64];
  __shared__ int ccount;

  const int nf = flag[0];
  if (blockIdx.x >= nf) return;
  const int tid = threadIdx.x, w = tid >> 6, lane = tid & 63;
  const int i = flag[1 + blockIdx.x];
  const int ti = tgt[i];
  if (tid < DD) xi[tid] = x[(size_t)i * DD + tid];
  __syncthreads();

  float sims[16];
  const float4* xiv = reinterpret_cast<const float4*>(xi);
  for (int c = 0; c < 16; ++c) {
    const int j = (c << 8) + tid;
    const float4* xj = reinterpret_cast<const float4*>(x + (size_t)j * DD);
    float a0 = 0, a1 = 0, a2 = 0, a3 = 0;
    #pragma unroll
    for (int d = 0; d < 32; ++d) {
      float4 u = xiv[d]; float4 v = xj[d];
      a0 = fmaf(u.x, v.x, a0); a1 = fmaf(u.y, v.y, a1);
      a2 = fmaf(u.z, v.z, a2); a3 = fmaf(u.w, v.w, a3);
    }
    sims[c] = (a0 + a1) + (a2 + a3);
  }

  double sx0 = (double)xi[lane], sx1 = (double)xi[lane + 64];
  const double selfd = wsum_d(sx0 * sx0 + sx1 * sx1);
  const bool self_pos = (selfd < 1.0);

  unsigned kv[16];
  double bs = 0.0;
  #pragma unroll
  for (int c = 0; c < 16; ++c) { bs += (double)sims[c]; kv[c] = f2k(sims[c]); }
  if (!self_pos && ((i & 255) == tid)) kv[i >> 8] = 0xFFFFFFFFu;

  bs = wsum_d(bs);
  if (lane == 0) redD[w] = bs;
  __syncthreads();
  const float basef = (float)((redD[0] + redD[1] + redD[2] + redD[3]) * (1.0 / NN));

  unsigned lo = 0;
  int nLo = 0, nHi = NN, b = 31, par = 0;
  while (b >= 0 && (nHi - nLo) > 64) {
    unsigned mid = lo | (1u << b);
    int c = 0;
    #pragma unroll
    for (int t = 0; t < 16; ++t) c += (kv[t] < mid) ? 1 : 0;
    c = wsum_i(c);
    if (lane == 0) redI[par][w] = c;
    __syncthreads();
    c = redI[par][0] + redI[par][1] + redI[par][2] + redI[par][3];
    par ^= 1;
    if (c <= KSEL) { lo = mid; nLo = c; }
    else nHi = c;
    --b;
  }
  unsigned keysel;
  if ((nHi - nLo) <= 64) {
    const int shift = b + 1;
    const unsigned pfx = lo >> shift;
    if (tid == 0) ccount = 0;
    __syncthreads();
    #pragma unroll
    for (int t = 0; t < 16; ++t)
      if ((kv[t] >> shift) == pfx) { int p = atomicAdd(&ccount, 1); cbuf[p] = kv[t]; }
    __syncthreads();
    const int total = ccount;
    unsigned v = cbuf[lane];
    unsigned long long amask = (total >= 64) ? ~0ull : ((1ull << total) - 1ull);
    int ww = KSEL - nLo;
    for (int bb = b; bb >= 0; --bb) {
      unsigned long long z = __ballot(((amask >> lane) & 1ull) &&
                                      (((v >> bb) & 1u) == 0u));
      int zc = __popcll(z);
      if (ww < zc) amask = z;
      else { ww -= zc; amask &= ~z; }
    }
    int first = __ffsll((unsigned long long)amask) - 1;
    keysel = __shfl(v, first, 64);
  } else {
    keysel = lo;
  }
  const float thr = k2f(keysel);

  double psum = 0.0, nsum = 0.0;
  float minp = __builtin_inff();
  int hasp = 0;
  double pss = 0.0, nss = 0.0;
  int pct = 0, nct = 0;
  #pragma unroll
  for (int c = 0; c < 16; ++c) {
    const int j = (c << 8) + tid;
    const float s = k2f(kv[c]);
    const bool same = (tgt[j] == ti);
    const bool vpos = same && ((j == i) ? self_pos : (s < 1.0f));
    if (vpos) { minp = fminf(minp, s); pss += (double)s; pct++; }
    if (!same) { nss += (double)s; nct++; }
    if (s < thr) {
      float wgt = expf(ALPHA_C * (basef - s));
      if (vpos) { psum += (double)wgt; hasp = 1; }
      else if (!same) nsum += (double)wgt;
    }
  }
  psum = wsum_d(psum); nsum = wsum_d(nsum);
  minp = wmin_f(minp); hasp = wsum_i(hasp);
  if (lane == 0) { redP[w] = psum; redN[w] = nsum; redM[w] = minp; redH[w] = hasp; }
  __syncthreads();
  const double tpsum = redP[0] + redP[1] + redP[2] + redP[3];
  const double tnsum = redN[0] + redN[1] + redN[2] + redN[3];
  const float  tminp = fminf(fminf(redM[0], redM[1]), fminf(redM[2], redM[3]));
  const int    thasp = redH[0] + redH[1] + redH[2] + redH[3];

  if (i == NN - 1) {
    __syncthreads();
    pss = wsum_d(pss); nss = wsum_d(nss);
    pct = wsum_i(pct); nct = wsum_i(nct);
    if (lane == 0) { redP[w] = pss; redN[w] = nss; redC[w] = pct; redC2[w] = nct; }
    __syncthreads();
    if (tid == 0) {
      out[2] = (float)((redP[0] + redP[1] + redP[2] + redP[3]) /
                       (double)(redC[0] + redC[1] + redC[2] + redC[3]));
      out[3] = (float)((redN[0] + redN[1] + redN[2] + redN[3]) /
                       (double)(redC2[0] + redC2[1] + redC2[2] + redC2[3]));
    }
  }
  if (tid == 0) {
    float pl = (thasp > 0) ? (float)tpsum : expf(ALPHA_C * (basef - tminp));
    row_loss[i] = -logf(pl / (pl + (float)tnsum));
  }
}

// ---- kernel 5: deterministic mean of per-row losses ----
__global__ void nca_final(const float* __restrict__ row_loss, float* __restrict__ out) {
  __shared__ double redd[4];
  int tid = threadIdx.x;
  double s = 0.0;
  for (int i = tid; i < NN; i += 256) s += (double)row_loss[i];
  #pragma unroll
  for (int m = 32; m; m >>= 1) s += __shfl_xor(s, m, 64);
  if ((tid & 63) == 0) redd[tid >> 6] = s;
  __syncthreads();
  if (tid == 0) {
    double tot = redd[0] + redd[1] + redd[2] + redd[3];
    out[0] = (float)(tot * (1.0 / NN));
    out[1] = 0.0f;
  }
}

extern "C" void kernel_launch(void* const* d_in, const int* in_sizes, int n_in,
                              void* d_out, int out_size, void* d_ws, size_t ws_size,
                              hipStream_t stream) {
  const float* x  = (const float*)d_in[0];
  const int* tgt  = (const int*)d_in[1];
  float* out      = (float*)d_out;

  // ws: xhi 1MB | xlo 1MB | row_loss 16KB | winbuf 8MB | wcbuf 64KB | diagneg | flag
  short* xhi      = (short*)d_ws;
  short* xlo      = xhi + (size_t)NN * DD;
  float* row_loss = (float*)(xlo + (size_t)NN * DD);
  uint2* winbuf   = (uint2*)(row_loss + NN);
  unsigned char* wcbuf = (unsigned char*)(winbuf + (size_t)NN * 256);
  float* diagneg  = (float*)(wcbuf + (size_t)NN * 16);
  int* flag       = (int*)(diagneg + 64);

  nca_prep<<<(NN * DD / 8) / 256, 256, 0, stream>>>(x, xhi, xlo, flag);
  nca_gemm<<<(NN / 32) * (NN / 256), 256, 0, stream>>>(xhi, xlo, tgt, winbuf, wcbuf, diagneg);
  nca_combine<<<NN / 4, 256, 0, stream>>>(x, tgt, winbuf, wcbuf, diagneg, flag, row_loss, out);
  nca_fallback<<<NN, 256, 0, stream>>>(x, tgt, flag, row_loss, out);
  nca_final<<<1, 256, 0, stream>>>(row_loss, out);
}

// Round 18
// 47.537 us; speedup vs baseline: 8.5929x; 1.0396x over previous
//
#include <hip/hip_runtime.h>
#include <math.h>

#define NN 4096
#define DD 128
#define ALPHA_C 16.0f
#define KSEL 32         // threshold = (K+1)-th smallest, 0-based index K
#define P2F -0.19f      // pivot: rank-32 of N(0,1/128) sims is ~-0.213, below P2
#define SLOTS 16        // slots per (row, colblock); appends ~Poisson(4.6)

typedef __attribute__((ext_vector_type(8))) short bf16x8;
typedef __attribute__((ext_vector_type(4))) float f32x4;

// ---- float <-> order-preserving u32 key ----
__device__ __forceinline__ unsigned f2k(float f) {
  unsigned b = __float_as_uint(f);
  return (b & 0x80000000u) ? ~b : (b | 0x80000000u);
}
__device__ __forceinline__ float k2f(unsigned k) {
  unsigned b = (k & 0x80000000u) ? (k & 0x7FFFFFFFu) : ~k;
  return __uint_as_float(b);
}

// ---- wave (64-lane) butterfly reductions ----
__device__ __forceinline__ double wsum_d(double v) {
  #pragma unroll
  for (int m = 32; m; m >>= 1) v += __shfl_xor(v, m, 64);
  return v;
}
__device__ __forceinline__ int wsum_i(int v) {
  #pragma unroll
  for (int m = 32; m; m >>= 1) v += __shfl_xor(v, m, 64);
  return v;
}
__device__ __forceinline__ float wsum_f(float v) {
  #pragma unroll
  for (int m = 32; m; m >>= 1) v += __shfl_xor(v, m, 64);
  return v;
}
__device__ __forceinline__ float wmin_f(float v) {
  #pragma unroll
  for (int m = 32; m; m >>= 1) v = fminf(v, __shfl_xor(v, m, 64));
  return v;
}

// ---- kernel 1: split x -> bf16 hi/lo fragment-major; f64 self-dots ----
// Block b covers exactly rows 16b..16b+15 (16 threads per row).
__global__ __launch_bounds__(256) void nca_prep(
    const float* __restrict__ x, short* __restrict__ xhi, short* __restrict__ xlo,
    double* __restrict__ selfdot, int* __restrict__ flag) {
  __shared__ double sd[16][16];

  const int tid = threadIdx.x;
  const int f  = blockIdx.x * 256 + tid;   // 0 .. N*D/8-1
  if (f == 0) flag[0] = 0;
  const int l  = f & 63;
  const int kb = (f >> 6) & 3;
  const int rg = f >> 8;                   // == blockIdx.x
  const int rloc = l & 15;
  const int row = (rg << 4) + rloc;
  const int k0  = (kb << 5) + ((l >> 4) << 3);
  const float* src = x + (size_t)row * DD + k0;
  float4 v0 = *reinterpret_cast<const float4*>(src);
  float4 v1 = *reinterpret_cast<const float4*>(src + 4);
  float vv[8] = {v0.x, v0.y, v0.z, v0.w, v1.x, v1.y, v1.z, v1.w};
  bf16x8 h, lo;
  double sdp = 0.0;
  #pragma unroll
  for (int q = 0; q < 8; ++q) {
    sdp += (double)vv[q] * (double)vv[q];
    unsigned u  = __float_as_uint(vv[q]);
    unsigned hb = (u + 0x7FFFu + ((u >> 16) & 1u)) >> 16;
    float hf    = __uint_as_float(hb << 16);
    float lf    = vv[q] - hf;
    unsigned ul = __float_as_uint(lf);
    unsigned lb = (ul + 0x7FFFu + ((ul >> 16) & 1u)) >> 16;
    h[q] = (short)hb; lo[q] = (short)lb;
  }
  *reinterpret_cast<bf16x8*>(xhi + (size_t)f * 8) = h;
  *reinterpret_cast<bf16x8*>(xlo + (size_t)f * 8) = lo;

  // deterministic per-row f64 self-dot: 16 partials per row, fixed-order sum
  sd[rloc][(tid >> 4)] = sdp;
  __syncthreads();
  if (tid < 16) {
    double s = 0.0;
    #pragma unroll
    for (int q = 0; q < 16; ++q) s += sd[tid][q];
    selfdot[(rg << 4) + tid] = s;
  }
}

// ---- kernel 2: fused MFMA GEMM + MINIMAL epilogue (XCD-chunked swizzle) ----
// Exports only: (a) candidate list per row = all values with key<P2 plus ALL
// non-self same-class values (tagged), into fixed slots winbuf[row][cg*16+s];
// (b) true per-(row,cg) counts wcbuf; (c) last-row neg sum (16 diag blocks).
// base is DROPPED: loss = -log(pl/(pl+nl)) is invariant to exp(alpha*base).
__global__ __launch_bounds__(256) void nca_gemm(
    const short* __restrict__ xhi, const short* __restrict__ xlo,
    const int* __restrict__ tgt, uint2* __restrict__ winbuf,
    unsigned char* __restrict__ wcbuf, float* __restrict__ diagneg) {
  __shared__ int wcl[32];                // per-(row,cg) append counters

  const int tid = threadIdx.x;
  const int w   = tid >> 6;
  const int l   = tid & 63;
  // XCD-chunked bijective swizzle (2048 blocks, 8 XCDs): each XCD gets a
  // contiguous 256-block chunk = 16 rgs x 16 cgs -> packed operands (2MB)
  // become XCD-L2-resident. Perf-only; any mapping is correct.
  const int bid = blockIdx.x;
  const int swz = ((bid & 7) << 8) + (bid >> 3);
  const int rg  = swz >> 4;
  const int cg  = swz & 15;
  const int R   = rg << 5;                 // 32 rows
  const int C   = (cg << 8) + (w << 6);    // 64 cols per wave
  const int rga = rg << 1;
  const int rgb = (cg << 4) + (w << 2);

  if (tid < 32) wcl[tid] = 0;
  __syncthreads();

  f32x4 acc[2][4];
  #pragma unroll
  for (int rt = 0; rt < 2; ++rt)
    #pragma unroll
    for (int t = 0; t < 4; ++t) acc[rt][t] = (f32x4){0.f, 0.f, 0.f, 0.f};

  #pragma unroll
  for (int kb = 0; kb < 4; ++kb) {
    bf16x8 ah[2], al[2], bh[4], bl[4];
    #pragma unroll
    for (int rt = 0; rt < 2; ++rt) {
      const size_t off = ((size_t)((rga + rt) * 4 + kb) * 64 + l) * 8;
      ah[rt] = *reinterpret_cast<const bf16x8*>(xhi + off);
      al[rt] = *reinterpret_cast<const bf16x8*>(xlo + off);
    }
    #pragma unroll
    for (int t = 0; t < 4; ++t) {
      const size_t off = ((size_t)((rgb + t) * 4 + kb) * 64 + l) * 8;
      bh[t] = *reinterpret_cast<const bf16x8*>(xhi + off);
      bl[t] = *reinterpret_cast<const bf16x8*>(xlo + off);
    }
    #pragma unroll
    for (int rt = 0; rt < 2; ++rt)
      #pragma unroll
      for (int t = 0; t < 4; ++t) {
        acc[rt][t] = __builtin_amdgcn_mfma_f32_16x16x32_bf16(ah[rt], bh[t], acc[rt][t], 0, 0, 0);
        acc[rt][t] = __builtin_amdgcn_mfma_f32_16x16x32_bf16(ah[rt], bl[t], acc[rt][t], 0, 0, 0);
        acc[rt][t] = __builtin_amdgcn_mfma_f32_16x16x32_bf16(al[rt], bh[t], acc[rt][t], 0, 0, 0);
      }
  }

  // ---- minimal epilogue ----
  // C/D layout (m89-verified): col = lane&15, row = (lane>>4)*4 + reg
  const int rbase = (l >> 4) << 2;
  const int cc    = l & 15;
  const unsigned P2k = f2k(P2F);
  const bool diagblk = (R + 32 == NN);

  int tr[2][4], tc[4];
  #pragma unroll
  for (int rt = 0; rt < 2; ++rt)
    #pragma unroll
    for (int r = 0; r < 4; ++r) tr[rt][r] = tgt[R + (rt << 4) + rbase + r];
  #pragma unroll
  for (int t = 0; t < 4; ++t) tc[t] = tgt[C + (t << 4) + cc];

  #pragma unroll
  for (int rt = 0; rt < 2; ++rt) {
    #pragma unroll
    for (int r = 0; r < 4; ++r) {
      const int row_l = (rt << 4) + rbase + r;
      const int grow  = R + row_l;
      #pragma unroll
      for (int t = 0; t < 4; ++t) {
        const float s = acc[rt][t][r];
        const int j = C + (t << 4) + cc;
        const bool same = (tc[t] == tr[rt][r]);
        const unsigned key = f2k(s);
        const bool app = (j != grow) && (same || (key < P2k));
        if (app) {
          int slot = atomicAdd(&wcl[row_l], 1);
          if (slot < SLOTS)
            winbuf[(size_t)grow * 256 + (cg << 4) + slot] =
                make_uint2(key, same ? 1u : 0u);
        }
      }
    }
  }

  if (diagblk) {   // last-row (NN-1) negative-pair sim sum, 16 blocks only
    const int tN1 = tgt[NN - 1];
    float negs = 0.f;
    #pragma unroll
    for (int t = 0; t < 4; ++t)
      negs += (tc[t] != tN1) ? acc[1][t][3] : 0.f;
    negs = ((l >> 4) == 3) ? negs : 0.f;   // only group 3 holds row NN-1
    #pragma unroll
    for (int m = 1; m < 16; m <<= 1) negs += __shfl_xor(negs, m, 64);
    if (l == 48) diagneg[(cg << 2) + w] = negs;
  }

  __syncthreads();
  if (tid < 32) {
    int c = wcl[tid];
    wcbuf[(size_t)(R + tid) * 16 + cg] = (unsigned char)(c > 255 ? 255 : c);
  }
}

// ---- kernel 3: per-row combine. 1 wave = 1 row; complete info from list. ----
__global__ __launch_bounds__(256) void nca_combine(
    const double* __restrict__ selfdot, const int* __restrict__ tgt,
    const uint2* __restrict__ winbuf, const unsigned char* __restrict__ wcbuf,
    const float* __restrict__ diagneg, int* __restrict__ flag,
    float* __restrict__ row_loss, float* __restrict__ out) {
  const int tid = threadIdx.x, w = tid >> 6, lane = tid & 63;
  const int i = blockIdx.x * 4 + w;

  const double selfd = selfdot[i];
  const bool self_pos = (selfd < 1.0);

  // per-cg true counts; overflow -> exact fallback
  const int wcq_l = (lane < 16) ? (int)wcbuf[(size_t)i * 16 + lane] : 0;
  const bool ovf = (__ballot(wcq_l > SLOTS) != 0ull);

  // gather 4 fixed slots/lane: sigma = q*64+lane; cg = sigma>>4, slot = sigma&15
  unsigned k[4]  = {0xFFFFFFFFu, 0xFFFFFFFFu, 0xFFFFFFFFu, 0xFFFFFFFFu};
  unsigned sm[4] = {0u, 0u, 0u, 0u};
  #pragma unroll
  for (int q = 0; q < 4; ++q) {
    const int sigma = (q << 6) + lane;
    const int wcq = __shfl(wcq_l, sigma >> 4, 64);
    if ((sigma & 15) < (wcq < SLOTS ? wcq : SLOTS)) {
      uint2 e = winbuf[(size_t)i * 256 + sigma];
      k[q] = e.x; sm[q] = e.y;
    }
  }

  const unsigned P2k = f2k(P2F);
  int c2 = 0;
  #pragma unroll
  for (int q = 0; q < 4; ++q) c2 += (int)__popcll(__ballot(k[q] < P2k));
  const bool fast = (c2 > KSEL) && (!ovf);
  if (!fast) {
    if (lane == 0) { int p = atomicAdd(&flag[0], 1); flag[1 + p] = i; }
    return;
  }

  // exact rank-KSEL key: max u with count(keys < u) <= KSEL. Guard ensures
  // thrkey < P2k, where the list contains ALL row keys -> exact row rank.
  unsigned thrkey = 0;
  for (int b = 31; b >= 0; --b) {
    unsigned mid = thrkey | (1u << b);
    int c = 0;
    #pragma unroll
    for (int q = 0; q < 4; ++q) c += (int)__popcll(__ballot(k[q] < mid));
    if (c <= KSEL) thrkey = mid;
  }

  // weighted sums (base dropped: ratio-invariant), minpos, haspos
  float wp = 0.f, wn = 0.f, minp = __builtin_inff();
  int hp = 0;
  #pragma unroll
  for (int q = 0; q < 4; ++q) {
    const float s = k2f(k[q]);           // NaN for empty slots (sm=0, k=max)
    if (k[q] < thrkey) {
      float e = expf(-ALPHA_C * s);
      if (sm[q]) { wp += e; hp = 1; } else wn += e;
    }
    if (sm[q] && s < 1.0f) minp = fminf(minp, s);
  }
  wp = wsum_f(wp); wn = wsum_f(wn); hp = wsum_i(hp); minp = wmin_f(minp);

  const float minp2 = self_pos ? fminf(minp, (float)selfd) : minp;
  const float pl = hp ? wp : expf(-ALPHA_C * minp2);
  const float nl = wn;
  if (lane == 0) row_loss[i] = -logf(pl / (pl + nl));

  if (i == NN - 1) {                     // diagnostics from the last row
    float ps = 0.f; int pc = 0;
    #pragma unroll
    for (int q = 0; q < 4; ++q) {
      const float s = k2f(k[q]);
      if (sm[q] && s < 1.0f) { ps += s; pc++; }
    }
    ps = wsum_f(ps); pc = wsum_i(pc);
    float ns = wsum_f(diagneg[lane]);    // 64 partials from 16 diag blocks
    const int ti = tgt[NN - 1];
    int nc = 0;
    #pragma unroll
    for (int kk = 0; kk < 16; ++kk) {
      int4 t4 = *reinterpret_cast<const int4*>(tgt + (kk << 8) + (lane << 2));
      nc += (t4.x != ti) + (t4.y != ti) + (t4.z != ti) + (t4.w != ti);
    }
    nc = wsum_i(nc);
    if (lane == 0) {
      out[2] = (ps + (self_pos ? (float)selfd : 0.f)) /
               (float)(pc + (self_pos ? 1 : 0));
      out[3] = ns / (float)nc;
    }
  }
}

// ---- kernel 4: exact fallback, 1 block per flagged row (early exit) ----
__global__ __launch_bounds__(256) void nca_fallback(
    const float* __restrict__ x, const int* __restrict__ tgt,
    const int* __restrict__ flag, float* __restrict__ row_loss,
    float* __restrict__ out) {
  __shared__ float xi[DD];
  __shared__ double redD[4];
  __shared__ int redI[2][4];
  __shared__ double redP[4], redN[4];
  __shared__ float redM[4];
  __shared__ int redH[4], redC[4], redC2[4];
  __shared__ unsigned cbuf[64];
  __shared__ int ccount;

  const int nf = flag[0];
  if (blockIdx.x >= nf) return;
  const int tid = threadIdx.x, w = tid >> 6, lane = tid & 63;
  const int i = flag[1 + blockIdx.x];
  const int ti = tgt[i];
  if (tid < DD) xi[tid] = x[(size_t)i * DD + tid];
  __syncthreads();

  float sims[16];
  const float4* xiv = reinterpret_cast<const float4*>(xi);
  for (int c = 0; c < 16; ++c) {
    const int j = (c << 8) + tid;
    const float4* xj = reinterpret_cast<const float4*>(x + (size_t)j * DD);
    float a0 = 0, a1 = 0, a2 = 0, a3 = 0;
    #pragma unroll
    for (int d = 0; d < 32; ++d) {
      float4 u = xiv[d]; float4 v = xj[d];
      a0 = fmaf(u.x, v.x, a0); a1 = fmaf(u.y, v.y, a1);
      a2 = fmaf(u.z, v.z, a2); a3 = fmaf(u.w, v.w, a3);
    }
    sims[c] = (a0 + a1) + (a2 + a3);
  }

  double sx0 = (double)xi[lane], sx1 = (double)xi[lane + 64];
  const double selfd = wsum_d(sx0 * sx0 + sx1 * sx1);
  const bool self_pos = (selfd < 1.0);

  unsigned kv[16];
  double bs = 0.0;
  #pragma unroll
  for (int c = 0; c < 16; ++c) { bs += (double)sims[c]; kv[c] = f2k(sims[c]); }
  if (!self_pos && ((i & 255) == tid)) kv[i >> 8] = 0xFFFFFFFFu;

  bs = wsum_d(bs);
  if (lane == 0) redD[w] = bs;
  __syncthreads();
  const float basef = (float)((redD[0] + redD[1] + redD[2] + redD[3]) * (1.0 / NN));

  unsigned lo = 0;
  int nLo = 0, nHi = NN, b = 31, par = 0;
  while (b >= 0 && (nHi - nLo) > 64) {
    unsigned mid = lo | (1u << b);
    int c = 0;
    #pragma unroll
    for (int t = 0; t < 16; ++t) c += (kv[t] < mid) ? 1 : 0;
    c = wsum_i(c);
    if (lane == 0) redI[par][w] = c;
    __syncthreads();
    c = redI[par][0] + redI[par][1] + redI[par][2] + redI[par][3];
    par ^= 1;
    if (c <= KSEL) { lo = mid; nLo = c; }
    else nHi = c;
    --b;
  }
  unsigned keysel;
  if ((nHi - nLo) <= 64) {
    const int shift = b + 1;
    const unsigned pfx = lo >> shift;
    if (tid == 0) ccount = 0;
    __syncthreads();
    #pragma unroll
    for (int t = 0; t < 16; ++t)
      if ((kv[t] >> shift) == pfx) { int p = atomicAdd(&ccount, 1); cbuf[p] = kv[t]; }
    __syncthreads();
    const int total = ccount;
    unsigned v = cbuf[lane];
    unsigned long long amask = (total >= 64) ? ~0ull : ((1ull << total) - 1ull);
    int ww = KSEL - nLo;
    for (int bb = b; bb >= 0; --bb) {
      unsigned long long z = __ballot(((amask >> lane) & 1ull) &&
                                      (((v >> bb) & 1u) == 0u));
      int zc = __popcll(z);
      if (ww < zc) amask = z;
      else { ww -= zc; amask &= ~z; }
    }
    int first = __ffsll((unsigned long long)amask) - 1;
    keysel = __shfl(v, first, 64);
  } else {
    keysel = lo;
  }
  const float thr = k2f(keysel);

  double psum = 0.0, nsum = 0.0;
  float minp = __builtin_inff();
  int hasp = 0;
  double pss = 0.0, nss = 0.0;
  int pct = 0, nct = 0;
  #pragma unroll
  for (int c = 0; c < 16; ++c) {
    const int j = (c << 8) + tid;
    const float s = k2f(kv[c]);
    const bool same = (tgt[j] == ti);
    const bool vpos = same && ((j == i) ? self_pos : (s < 1.0f));
    if (vpos) { minp = fminf(minp, s); pss += (double)s; pct++; }
    if (!same) { nss += (double)s; nct++; }
    if (s < thr) {
      float wgt = expf(ALPHA_C * (basef - s));
      if (vpos) { psum += (double)wgt; hasp = 1; }
      else if (!same) nsum += (double)wgt;
    }
  }
  psum = wsum_d(psum); nsum = wsum_d(nsum);
  minp = wmin_f(minp); hasp = wsum_i(hasp);
  if (lane == 0) { redP[w] = psum; redN[w] = nsum; redM[w] = minp; redH[w] = hasp; }
  __syncthreads();
  const double tpsum = redP[0] + redP[1] + redP[2] + redP[3];
  const double tnsum = redN[0] + redN[1] + redN[2] + redN[3];
  const float  tminp = fminf(fminf(redM[0], redM[1]), fminf(redM[2], redM[3]));
  const int    thasp = redH[0] + redH[1] + redH[2] + redH[3];

  if (i == NN - 1) {
    __syncthreads();
    pss = wsum_d(pss); nss = wsum_d(nss);
    pct = wsum_i(pct); nct = wsum_i(nct);
    if (lane == 0) { redP[w] = pss; redN[w] = nss; redC[w] = pct; redC2[w] = nct; }
    __syncthreads();
    if (tid == 0) {
      out[2] = (float)((redP[0] + redP[1] + redP[2] + redP[3]) /
                       (double)(redC[0] + redC[1] + redC[2] + redC[3]));
      out[3] = (float)((redN[0] + redN[1] + redN[2] + redN[3]) /
                       (double)(redC2[0] + redC2[1] + redC2[2] + redC2[3]));
    }
  }
  if (tid == 0) {
    float pl = (thasp > 0) ? (float)tpsum : expf(ALPHA_C * (basef - tminp));
    row_loss[i] = -logf(pl / (pl + (float)tnsum));
  }
}

// ---- kernel 5: deterministic mean of per-row losses ----
__global__ void nca_final(const float* __restrict__ row_loss, float* __restrict__ out) {
  __shared__ double redd[4];
  int tid = threadIdx.x;
  double s = 0.0;
  for (int i = tid; i < NN; i += 256) s += (double)row_loss[i];
  #pragma unroll
  for (int m = 32; m; m >>= 1) s += __shfl_xor(s, m, 64);
  if ((tid & 63) == 0) redd[tid >> 6] = s;
  __syncthreads();
  if (tid == 0) {
    double tot = redd[0] + redd[1] + redd[2] + redd[3];
    out[0] = (float)(tot * (1.0 / NN));
    out[1] = 0.0f;
  }
}

extern "C" void kernel_launch(void* const* d_in, const int* in_sizes, int n_in,
                              void* d_out, int out_size, void* d_ws, size_t ws_size,
                              hipStream_t stream) {
  const float* x  = (const float*)d_in[0];
  const int* tgt  = (const int*)d_in[1];
  float* out      = (float*)d_out;

  // ws: xhi 1MB | xlo 1MB | row_loss 16KB | selfdot 32KB | winbuf 8MB | wcbuf 64KB | diagneg | flag
  short* xhi      = (short*)d_ws;
  short* xlo      = xhi + (size_t)NN * DD;
  float* row_loss = (float*)(xlo + (size_t)NN * DD);
  double* selfdot = (double*)(row_loss + NN);
  uint2* winbuf   = (uint2*)(selfdot + NN);
  unsigned char* wcbuf = (unsigned char*)(winbuf + (size_t)NN * 256);
  float* diagneg  = (float*)(wcbuf + (size_t)NN * 16);
  int* flag       = (int*)(diagneg + 64);

  nca_prep<<<NN / 16, 256, 0, stream>>>(x, xhi, xlo, selfdot, flag);
  nca_gemm<<<(NN / 32) * (NN / 256), 256, 0, stream>>>(xhi, xlo, tgt, winbuf, wcbuf, diagneg);
  nca_combine<<<NN / 4, 256, 0, stream>>>(selfdot, tgt, winbuf, wcbuf, diagneg, flag, row_loss, out);
  nca_fallback<<<NN, 256, 0, stream>>>(x, tgt, flag, row_loss, out);
  nca_final<<<1, 256, 0, stream>>>(row_loss, out);
}